// Round 2
// baseline (829.809 us; speedup 1.0000x reference)
//
#include <hip/hip_runtime.h>
#include <cstdint>

// Requires ws_size >= ~195 MB (peak packed liveness; see layout in kernel_launch).

#define NTOK 8192
#define DM   512
#define DI   2048
#define NEXP 24
#define TPG  2048
#define CAP  171
#define CAPR 176
#define EPSF 1e-6f

typedef __bf16 bf16x8 __attribute__((ext_vector_type(8)));
typedef float f32x4 __attribute__((ext_vector_type(4)));

static __device__ __forceinline__ unsigned short f2bf(float f) {
  unsigned int u = __builtin_bit_cast(unsigned int, f);
  u = (u + 0x7fffu + ((u >> 16) & 1u)) >> 16;
  return (unsigned short)u;
}
static __device__ __forceinline__ unsigned int pk2(float a, float b) {
  return (unsigned int)f2bf(a) | ((unsigned int)f2bf(b) << 16);
}

// async global->LDS, 16B per lane; LDS dest is wave-uniform base + lane*16
static __device__ __forceinline__ void gload16(const unsigned short* g, unsigned short* l) {
  __builtin_amdgcn_global_load_lds(
      (const __attribute__((address_space(1))) void*)g,
      (__attribute__((address_space(3))) void*)l, 16, 0, 0);
}

// ---------------- weight transpose+convert: fp32 [e][K][N] -> bf16 [e][N][K]
// grid: (N/64, K/64, E), 256 threads
__global__ __launch_bounds__(256) void convw(
    const float* __restrict__ in, unsigned short* __restrict__ out, int K, int N)
{
  __shared__ unsigned short T[64][65];
  int e = blockIdx.z;
  const float* ip = in + (size_t)e * K * N;
  unsigned short* op = out + (size_t)e * N * K;
  int n0 = blockIdx.x * 64, k0 = blockIdx.y * 64;
  int tid = threadIdx.x;
  #pragma unroll
  for (int i = 0; i < 16; ++i) {
    int lin = tid + i * 256;
    int k = lin >> 6, n = lin & 63;
    T[n][k] = f2bf(ip[(size_t)(k0 + k) * N + n0 + n]);
  }
  __syncthreads();
  #pragma unroll
  for (int i = 0; i < 16; ++i) {
    int lin = tid + i * 256;
    int n = lin >> 6, k = lin & 63;
    op[(size_t)(n0 + n) * K + k0 + k] = T[n][k];
  }
}

// ---------------- elementwise fp32 -> bf16 (4 elems/thread)
__global__ __launch_bounds__(256) void convx(
    const float* __restrict__ in, unsigned short* __restrict__ out)
{
  int i = blockIdx.x * 256 + threadIdx.x;
  float4 v = ((const float4*)in)[i];
  uint2 p;
  p.x = pk2(v.x, v.y); p.y = pk2(v.z, v.w);
  ((uint2*)out)[i] = p;
}

// ---------------- unified bf16-MFMA GEMM, 64m x 128n tile, BK=64, 4 waves
// 2-phase double-buffered pipeline, global_load_lds staging, XOR-swizzled LDS.
// A: bf16 rows [*, lda], optionally gathered via lrow (pair*CAPR+m)
// Bt: bf16 pre-transposed [e][N][K]
// mode 0: Cb[m*N+col] = bf16(acc*scale)
// mode 1: Cf[m*N+col] = relu(acc) + Add[m*N+col]
// mode 2: atomicAdd(Cf[lrow[m]*N+col], lw[m]*(acc + bias[e*N+col]))
__global__ __launch_bounds__(256) void mfma_gemm(
    const unsigned short* __restrict__ A, int lda,
    const unsigned short* __restrict__ Bt,
    const float* __restrict__ bias,
    const int* __restrict__ lrow, const float* __restrict__ lw,
    const int* __restrict__ cnts,
    float* __restrict__ Cf, unsigned short* __restrict__ Cb,
    const float* __restrict__ Add,
    int M, int N, int K, int mode, float scale)
{
  // linear rows of 64 shorts (128B); granule (16B) XOR-swizzled by row&7
  __shared__ unsigned short As[2][64 * 64];
  __shared__ unsigned short Bs[2][128 * 64];
  int tid = threadIdx.x;
  int w = tid >> 6, lane = tid & 63, quad = lane >> 4, l16 = lane & 15;
  int n0 = blockIdx.x * 128;
  int m0 = blockIdx.y * 64;
  int pair = blockIdx.z;
  int e = pair % NEXP;
  int count = cnts ? cnts[pair] : M;
  if (m0 >= count) return;
  const int*   lr  = lrow ? lrow + pair * CAPR : nullptr;
  const float* lwp = lw   ? lw   + pair * CAPR : nullptr;

  int sub = lane >> 3;               // row-within-8-row wave chunk
  int gsw = (lane & 7) ^ sub;        // pre-swizzled source granule
  const unsigned short* aSrc[2];
  #pragma unroll
  for (int i = 0; i < 2; ++i) {
    int mm = m0 + i * 32 + w * 8 + sub;
    if (mm >= count) mm = count - 1;
    int rm = lr ? lr[mm] : mm;
    aSrc[i] = A + (size_t)rm * lda + gsw * 8;
  }
  const unsigned short* Bte = Bt + (size_t)e * N * K;
  const unsigned short* bSrc[4];
  #pragma unroll
  for (int i = 0; i < 4; ++i)
    bSrc[i] = Bte + (size_t)(n0 + i * 32 + w * 8 + sub) * K + gsw * 8;

  int wbase = w * 512;               // (w*8 rows) * 64 shorts

  f32x4 acc[4][2] = {};
  int nt = K >> 6;

  // prologue: stage tile 0 into buf 0
  #pragma unroll
  for (int i = 0; i < 2; ++i) gload16(aSrc[i], &As[0][i * 2048 + wbase]);
  #pragma unroll
  for (int i = 0; i < 4; ++i) gload16(bSrc[i], &Bs[0][i * 2048 + wbase]);

  for (int t = 0; t < nt; ++t) {
    asm volatile("s_waitcnt vmcnt(0)" ::: "memory");
    __syncthreads();
    int cur = t & 1;
    if (t + 1 < nt) {
      int koff = (t + 1) << 6;
      int nxt = cur ^ 1;
      #pragma unroll
      for (int i = 0; i < 2; ++i) gload16(aSrc[i] + koff, &As[nxt][i * 2048 + wbase]);
      #pragma unroll
      for (int i = 0; i < 4; ++i) gload16(bSrc[i] + koff, &Bs[nxt][i * 2048 + wbase]);
    }
    const unsigned short* Ab = As[cur];
    const unsigned short* Bb = Bs[cur];
    #pragma unroll
    for (int half = 0; half < 2; ++half) {
      int g8 = ((half * 4 + quad) ^ (l16 & 7)) * 8;   // swizzled read granule
      bf16x8 af[4];
      #pragma unroll
      for (int ms = 0; ms < 4; ++ms)
        af[ms] = *(const bf16x8*)&Ab[(ms * 16 + l16) * 64 + g8];
      bf16x8 bfr[2];
      #pragma unroll
      for (int ns = 0; ns < 2; ++ns)
        bfr[ns] = *(const bf16x8*)&Bb[(w * 32 + ns * 16 + l16) * 64 + g8];
      #pragma unroll
      for (int ms = 0; ms < 4; ++ms)
        #pragma unroll
        for (int ns = 0; ns < 2; ++ns)
          acc[ms][ns] = __builtin_amdgcn_mfma_f32_16x16x32_bf16(af[ms], bfr[ns], acc[ms][ns], 0, 0, 0);
    }
  }
  // ---- epilogue
  float bv[2];
  if (mode == 2) {
    #pragma unroll
    for (int ns = 0; ns < 2; ++ns)
      bv[ns] = bias[(size_t)e * N + n0 + w * 32 + ns * 16 + l16];
  }
  #pragma unroll
  for (int ms = 0; ms < 4; ++ms) {
    #pragma unroll
    for (int ns = 0; ns < 2; ++ns) {
      int col = n0 + w * 32 + ns * 16 + l16;
      #pragma unroll
      for (int r = 0; r < 4; ++r) {
        int m = m0 + ms * 16 + quad * 4 + r;
        if (mode == 0) {
          Cb[(size_t)m * N + col] = f2bf(acc[ms][ns][r] * scale);
        } else if (mode == 1) {
          Cf[(size_t)m * N + col] = fmaxf(acc[ms][ns][r], 0.f) + Add[(size_t)m * N + col];
        } else {
          if (m < count) {
            int rr = lr[m];
            float wgt = lwp[m];
            atomicAdd(&Cf[(size_t)rr * N + col], wgt * (acc[ms][ns][r] + bv[ns]));
          }
        }
      }
    }
  }
}

// ---------------- MFMA bf16 flash attention (ctx written as bf16)
__global__ __launch_bounds__(256) void attn_mfma(
    const unsigned short* __restrict__ Qb, const unsigned short* __restrict__ Kb,
    const unsigned short* __restrict__ Vb, unsigned short* __restrict__ ctx)
{
  __shared__ unsigned short Ks[64 * 72];
  __shared__ unsigned short Vt[64 * 72];
  __shared__ unsigned short Ps[4][16 * 72];
  int tid = threadIdx.x;
  int w = tid >> 6, lane = tid & 63, quad = lane >> 4, l16 = lane & 15;
  int qt = blockIdx.x, bh = blockIdx.y;
  int b = bh >> 3, h = bh & 7;
  size_t hoff = (size_t)h * 64;
  size_t tokbase = (size_t)b * 1024;

  int qrow = qt * 64 + w * 16 + l16;
  const unsigned short* qp = Qb + (tokbase + qrow) * 512 + hoff + quad * 8;
  bf16x8 qa0 = *(const bf16x8*)(qp);
  bf16x8 qa1 = *(const bf16x8*)(qp + 32);

  f32x4 O[4] = {};
  float mrow[4], lrowv[4];
  #pragma unroll
  for (int r = 0; r < 4; ++r) { mrow[r] = -1e30f; lrowv[r] = 0.f; }

  for (int kv0 = 0; kv0 < 1024; kv0 += 64) {
    __syncthreads();
    {
      const unsigned short* kg = Kb + (tokbase + kv0) * 512 + hoff;
      #pragma unroll
      for (int i = 0; i < 2; ++i) {
        int f = tid + i * 256;
        int key = f >> 3, c = f & 7;
        *(uint4*)&Ks[key * 72 + c * 8] = *(const uint4*)(kg + (size_t)key * 512 + c * 8);
      }
      const unsigned short* vg = Vb + (tokbase + kv0) * 512 + hoff;
      int d = tid & 63;
      #pragma unroll
      for (int i = 0; i < 2; ++i) {
        int ko = (tid >> 6) + i * 4;
        const unsigned short* vq = vg + (size_t)ko * 8 * 512 + d;
        unsigned int a0 = vq[0],        a1 = vq[512];
        unsigned int a2 = vq[2 * 512],  a3 = vq[3 * 512];
        unsigned int a4 = vq[4 * 512],  a5 = vq[5 * 512];
        unsigned int a6 = vq[6 * 512],  a7 = vq[7 * 512];
        uint4 pk;
        pk.x = a0 | (a1 << 16); pk.y = a2 | (a3 << 16);
        pk.z = a4 | (a5 << 16); pk.w = a6 | (a7 << 16);
        *(uint4*)&Vt[d * 72 + ko * 8] = pk;
      }
    }
    __syncthreads();

    f32x4 s[4];
    #pragma unroll
    for (int kt = 0; kt < 4; ++kt) {
      const unsigned short* kr = &Ks[(kt * 16 + l16) * 72 + quad * 8];
      bf16x8 kb0 = *(const bf16x8*)(kr);
      bf16x8 kb1 = *(const bf16x8*)(kr + 32);
      f32x4 z = {};
      z = __builtin_amdgcn_mfma_f32_16x16x32_bf16(qa0, kb0, z, 0, 0, 0);
      z = __builtin_amdgcn_mfma_f32_16x16x32_bf16(qa1, kb1, z, 0, 0, 0);
      s[kt] = z;
    }

    #pragma unroll
    for (int r = 0; r < 4; ++r) {
      float mx = fmaxf(fmaxf(s[0][r], s[1][r]), fmaxf(s[2][r], s[3][r]));
      mx = fmaxf(mx, __shfl_xor(mx, 1, 64));
      mx = fmaxf(mx, __shfl_xor(mx, 2, 64));
      mx = fmaxf(mx, __shfl_xor(mx, 4, 64));
      mx = fmaxf(mx, __shfl_xor(mx, 8, 64));
      float mnew = fmaxf(mrow[r], mx);
      float alpha = __expf(mrow[r] - mnew);
      mrow[r] = mnew;
      float psum = 0.f;
      #pragma unroll
      for (int kt = 0; kt < 4; ++kt) {
        float p = __expf(s[kt][r] - mnew);
        s[kt][r] = p;
        psum += p;
      }
      psum += __shfl_xor(psum, 1, 64);
      psum += __shfl_xor(psum, 2, 64);
      psum += __shfl_xor(psum, 4, 64);
      psum += __shfl_xor(psum, 8, 64);
      lrowv[r] = lrowv[r] * alpha + psum;
      #pragma unroll
      for (int dt = 0; dt < 4; ++dt) O[dt][r] *= alpha;
    }

    #pragma unroll
    for (int kt = 0; kt < 4; ++kt)
      #pragma unroll
      for (int r = 0; r < 4; ++r)
        Ps[w][(quad * 4 + r) * 72 + kt * 16 + l16] = f2bf(s[kt][r]);
    const unsigned short* pp = &Ps[w][l16 * 72 + quad * 8];
    bf16x8 pa0 = *(const bf16x8*)(pp);
    bf16x8 pa1 = *(const bf16x8*)(pp + 32);

    #pragma unroll
    for (int dt = 0; dt < 4; ++dt) {
      const unsigned short* vr = &Vt[(dt * 16 + l16) * 72 + quad * 8];
      bf16x8 vb0 = *(const bf16x8*)(vr);
      bf16x8 vb1 = *(const bf16x8*)(vr + 32);
      O[dt] = __builtin_amdgcn_mfma_f32_16x16x32_bf16(pa0, vb0, O[dt], 0, 0, 0);
      O[dt] = __builtin_amdgcn_mfma_f32_16x16x32_bf16(pa1, vb1, O[dt], 0, 0, 0);
    }
  }

  #pragma unroll
  for (int r = 0; r < 4; ++r) {
    float inv = 1.0f / lrowv[r];
    int row = qt * 64 + w * 16 + quad * 4 + r;
    unsigned short* cp = ctx + (tokbase + row) * 512 + hoff + l16;
    #pragma unroll
    for (int dt = 0; dt < 4; ++dt) cp[dt * 16] = f2bf(O[dt][r] * inv);
  }
}

// ---------------- layernorm (optional pre-add, post-relu, per-group params,
//                  dual fp32/bf16 outputs; in-place safe)
__global__ __launch_bounds__(256) void ln_kernel(
    const float* __restrict__ in, const float* __restrict__ add,
    float* __restrict__ out, unsigned short* __restrict__ outb,
    int D, int relu_after,
    const float* __restrict__ g0, const float* __restrict__ g1,
    const float* __restrict__ g2, const float* __restrict__ g3,
    const float* __restrict__ bb0, const float* __restrict__ bb1,
    const float* __restrict__ bb2, const float* __restrict__ bb3)
{
  int row = blockIdx.x;
  int grp = (row & 1023) >> 8;
  const float* g  = grp == 0 ? g0  : grp == 1 ? g1  : grp == 2 ? g2  : g3;
  const float* bb = grp == 0 ? bb0 : grp == 1 ? bb1 : grp == 2 ? bb2 : bb3;
  const float* ip = in + (size_t)row * D;
  const float* ap = add ? add + (size_t)row * D : nullptr;
  float vals[8];
  int per = D >> 8;
  float s1 = 0.f, s2 = 0.f;
  for (int i = 0; i < per; ++i) {
    int d = threadIdx.x + (i << 8);
    float vv = ip[d];
    if (ap) vv += ap[d];
    vals[i] = vv; s1 += vv; s2 += vv * vv;
  }
  #pragma unroll
  for (int o = 32; o; o >>= 1) { s1 += __shfl_xor(s1, o, 64); s2 += __shfl_xor(s2, o, 64); }
  __shared__ float sA[4], sB[4];
  int wid = threadIdx.x >> 6, lane = threadIdx.x & 63;
  if (lane == 0) { sA[wid] = s1; sB[wid] = s2; }
  __syncthreads();
  float t1 = sA[0] + sA[1] + sA[2] + sA[3];
  float t2 = sB[0] + sB[1] + sB[2] + sB[3];
  float mean = t1 / (float)D;
  float var = t2 / (float)D - mean * mean;
  float rs = rsqrtf(var + EPSF);
  float* op = out ? out + (size_t)row * D : nullptr;
  unsigned short* obp = outb ? outb + (size_t)row * D : nullptr;
  for (int i = 0; i < per; ++i) {
    int d = threadIdx.x + (i << 8);
    float o = (vals[i] - mean) * rs * g[d] + bb[d];
    if (relu_after) o = fmaxf(o, 0.f);
    if (op)  op[d] = o;
    if (obp) obp[d] = f2bf(o);
  }
}

// ---------------- gating stage 1
__global__ __launch_bounds__(256) void gate1(
    const float* __restrict__ xln, const float* __restrict__ wg,
    int* __restrict__ idx0, int* __restrict__ idx1,
    float* __restrict__ w0o, float* __restrict__ w1o)
{
  int wid = threadIdx.x >> 6, lane = threadIdx.x & 63;
  int tk = blockIdx.x * 4 + wid;
  int g = tk >> 11, t = tk & 2047;
  int b = t >> 8, j = t & 255;
  size_t row = (size_t)b * 1024 + g * 256 + j;
  const float* xp = xln + row * 512;
  float acc = -1e30f;
  if (lane < 24) {
    acc = 0.f;
    for (int d = 0; d < 512; ++d) acc += xp[d] * wg[d * 24 + lane];
  }
  float b0v = -1e30f, b1v = -1e30f; int i0 = 0, i1 = 0;
  for (int e = 0; e < 24; ++e) {
    float vv = __shfl(acc, e, 64);
    if (vv > b0v)      { b1v = b0v; i1 = i0; b0v = vv; i0 = e; }
    else if (vv > b1v) { b1v = vv; i1 = e; }
  }
  if (lane == 0) {
    float w0 = 1.0f / (1.0f + __expf(b1v - b0v));
    idx0[tk] = i0; idx1[tk] = i1; w0o[tk] = w0; w1o[tk] = 1.0f - w0;
  }
}

// ---------------- gating stage 2
__global__ __launch_bounds__(64) void gate2(
    const int* __restrict__ idx0, const int* __restrict__ idx1,
    const float* __restrict__ w0, const float* __restrict__ w1,
    int* __restrict__ lrow, float* __restrict__ lw, int* __restrict__ counts)
{
  int pair = blockIdx.x; int g = pair / 24; int e = pair % 24;
  int lane = threadIdx.x;
  int base = g * TPG;
  unsigned long long lm = (lane == 63) ? 0x7fffffffffffffffULL : ((1ULL << lane) - 1ULL);
  int run = 0;
  for (int it = 0; it < TPG / 64; ++it) {
    int t = it * 64 + lane;
    bool m = (idx0[base + t] == e);
    unsigned long long mask = __ballot(m);
    int pre = __popcll(mask & lm);
    int rank = run + pre;
    if (m && rank < CAP) {
      int bq = t >> 8, j = t & 255;
      lrow[pair * CAPR + rank] = bq * 1024 + g * 256 + j;
      lw[pair * CAPR + rank] = w0[base + t];
    }
    run += __popcll(mask);
  }
  int total1 = run;
  int run2 = 0;
  for (int it = 0; it < TPG / 64; ++it) {
    int t = it * 64 + lane;
    bool m = (idx1[base + t] == e);
    unsigned long long mask = __ballot(m);
    int pre = __popcll(mask & lm);
    int rank2 = run2 + pre;
    if (m && (total1 + rank2) < CAP) {
      int bq = t >> 8, j = t & 255;
      lrow[pair * CAPR + total1 + rank2] = bq * 1024 + g * 256 + j;
      lw[pair * CAPR + total1 + rank2] = w1[base + t];
    }
    run2 += __popcll(mask);
  }
  if (lane == 0) {
    int c1 = total1 < CAP ? total1 : CAP;
    int room = CAP - total1; if (room < 0) room = 0;
    int c2 = run2 < room ? run2 : room;
    counts[pair] = c1 + c2;
  }
}

extern "C" void kernel_launch(void* const* d_in, const int* in_sizes, int n_in,
                              void* d_out, int out_size, void* d_ws, size_t ws_size,
                              hipStream_t stream)
{
  const float* x   = (const float*)d_in[0];
  const float* wq  = (const float*)d_in[1];
  const float* wk  = (const float*)d_in[2];
  const float* wv  = (const float*)d_in[3];
  const float* wo  = (const float*)d_in[4];
  const float* ln_attn_g = (const float*)d_in[5];
  const float* ln_attn_b = (const float*)d_in[6];
  const float* wg1 = (const float*)d_in[7];
  const float* w1  = (const float*)d_in[8];
  const float* b1  = (const float*)d_in[9];
  const float* w2  = (const float*)d_in[11];
  const float* b2  = (const float*)d_in[12];
  const float* ln_out_g = (const float*)d_in[13];
  const float* ln_out_b = (const float*)d_in[14];
  const float* ln1g = (const float*)d_in[15]; const float* ln1b = (const float*)d_in[16];
  const float* ln2g = (const float*)d_in[17]; const float* ln2b = (const float*)d_in[18];
  const float* ln3g = (const float*)d_in[19]; const float* ln3b = (const float*)d_in[20];
  const float* ln4g = (const float*)d_in[21]; const float* ln4b = (const float*)d_in[22];

  char* ws = (char*)d_ws;
  const size_t MB = 1048576;
  unsigned short* wt1  = (unsigned short*)(ws + 0);
  unsigned short* wtq  = (unsigned short*)(ws + 48 * MB);
  unsigned short* wtk  = (unsigned short*)(ws + 48 * MB + 524288);
  unsigned short* wtv  = (unsigned short*)(ws + 49 * MB);
  unsigned short* wto  = (unsigned short*)(ws + 49 * MB + 524288);
  unsigned short* xbf  = (unsigned short*)(ws + 50 * MB);
  unsigned short* hb2  = (unsigned short*)(ws + 50 * MB);
  unsigned short* qbf  = (unsigned short*)(ws + 58 * MB);
  unsigned short* kbf  = (unsigned short*)(ws + 66 * MB);
  unsigned short* vbf  = (unsigned short*)(ws + 74 * MB);
  unsigned short* ctxb = (unsigned short*)(ws + 82 * MB);
  float* y0    = (float*)(ws + 90 * MB);
  float* ymoe  = (float*)(ws + 90 * MB);
  float* ctxln = (float*)(ws + 106 * MB);
  unsigned short* ctxlnb = (unsigned short*)(ws + 122 * MB);
  float* hb    = (float*)(ws + 130 * MB);
  unsigned short* wt2 = (unsigned short*)(ws + 130 * MB);
  char*  small = ws + 194 * MB;
  int*   idx0  = (int*)(small + 0);
  int*   idx1  = (int*)(small + 32768);
  float* w0a   = (float*)(small + 65536);
  float* w1a   = (float*)(small + 98304);
  int*   lrowp = (int*)(small + 131072);
  float* lwv   = (float*)(small + 198656);
  int*   cnts  = (int*)(small + 266240);

  dim3 blk(256);
  // ---- one-time conversions (bf16, B pre-transposed to [n][k])
  convw<<<dim3(8, 8, 1), blk, 0, stream>>>(wq, wtq, 512, 512);
  convw<<<dim3(8, 8, 1), blk, 0, stream>>>(wk, wtk, 512, 512);
  convw<<<dim3(8, 8, 1), blk, 0, stream>>>(wv, wtv, 512, 512);
  convw<<<dim3(8, 8, 1), blk, 0, stream>>>(wo, wto, 512, 512);
  convw<<<dim3(32, 8, 24), blk, 0, stream>>>(w1, wt1, 512, 2048);
  convx<<<4096, blk, 0, stream>>>(x, xbf);
  // ---- QKV projections: bf16 out (q scaled by 1/8)
  mfma_gemm<<<dim3(4, 128, 1), blk, 0, stream>>>(xbf, DM, wtq, nullptr, nullptr, nullptr, nullptr,
      nullptr, qbf, nullptr, NTOK, DM, DM, 0, 0.125f);
  mfma_gemm<<<dim3(4, 128, 1), blk, 0, stream>>>(xbf, DM, wtk, nullptr, nullptr, nullptr, nullptr,
      nullptr, kbf, nullptr, NTOK, DM, DM, 0, 1.0f);
  mfma_gemm<<<dim3(4, 128, 1), blk, 0, stream>>>(xbf, DM, wtv, nullptr, nullptr, nullptr, nullptr,
      nullptr, vbf, nullptr, NTOK, DM, DM, 0, 1.0f);
  // ---- attention (ctx out in bf16)
  attn_mfma<<<dim3(16, 64), blk, 0, stream>>>(qbf, kbf, vbf, ctxb);
  // ---- y0 = relu(ctx@wo) + x
  mfma_gemm<<<dim3(4, 128, 1), blk, 0, stream>>>(ctxb, DM, wto, nullptr, nullptr, nullptr, nullptr,
      y0, nullptr, x, NTOK, DM, DM, 1, 1.0f);
  // ---- ctx_ln = LN(y0), fp32 + bf16
  ln_kernel<<<8192, blk, 0, stream>>>(y0, nullptr, ctxln, ctxlnb, DM, 0,
      ln_attn_g, ln_attn_g, ln_attn_g, ln_attn_g, ln_attn_b, ln_attn_b, ln_attn_b, ln_attn_b);
  // ---- gating
  gate1<<<2048, blk, 0, stream>>>(ctxln, wg1, idx0, idx1, w0a, w1a);
  gate2<<<96, 64, 0, stream>>>(idx0, idx1, w0a, w1a, lrowp, lwv, cnts);
  // ---- zero accumulators
  hipMemsetAsync(hb, 0, (size_t)NTOK * DI * 4, stream);
  hipMemsetAsync(ymoe, 0, (size_t)NTOK * DM * 4, stream);
  // ---- MoE layer 1: hb += w * (ctxln@W1[e] + b1[e])
  mfma_gemm<<<dim3(16, 3, 96), blk, 0, stream>>>(ctxlnb, DM, wt1, b1, lrowp, lwv, cnts,
      hb, nullptr, nullptr, 0, DI, DM, 2, 1.0f);
  // ---- hb2 = bf16(relu(LN_g(hb)))
  ln_kernel<<<8192, blk, 0, stream>>>(hb, nullptr, nullptr, hb2, DI, 1,
      ln1g, ln2g, ln3g, ln4g, ln1b, ln2b, ln3b, ln4b);
  // ---- convert w2 into the now-dead hb region
  convw<<<dim3(8, 32, 24), blk, 0, stream>>>(w2, wt2, 2048, 512);
  // ---- MoE layer 2: ymoe += w * (hb2@W2[e] + b2[e])
  mfma_gemm<<<dim3(4, 3, 96), blk, 0, stream>>>(hb2, DI, wt2, b2, lrowp, lwv, cnts,
      ymoe, nullptr, nullptr, 0, DM, DI, 2, 1.0f);
  // ---- out = LN(ymoe + ctxln)
  ln_kernel<<<8192, blk, 0, stream>>>(ymoe, ctxln, (float*)d_out, nullptr, DM, 0,
      ln_out_g, ln_out_g, ln_out_g, ln_out_g, ln_out_b, ln_out_b, ln_out_b, ln_out_b);
}

// Round 3
// 776.367 us; speedup vs baseline: 1.0688x; 1.0688x over previous
//
#include <hip/hip_runtime.h>
#include <cstdint>

// ws layout (bytes, MB = 2^20):
// [0,48)    wt1 bf16 [24][2048][512]   : conv .. MoE1      } hb2 bf16 [0,32) : combine1 .. MoE2
// [48,96)   wt2 bf16 [24][512][2048]   : conv .. MoE2
// [96,112)  ctxln fp32                 : ctxLN .. final
// [112,120) ctxlnb bf16                : ctxLN .. MoE1
// [120,..)  early: xbf[120,128) qkvb[128,152) ctxb[152,160) wtqkv[160,161.5) wto[161.5,162) y0[162,178)
//           then: out1 bf16 [120,189.3) : MoE1 .. combine1 ; then out2 bf16 [120,137.3) : MoE2 .. final
// [190,..)  small gating buffers + ts0/ts1

#define NTOK 8192
#define DM   512
#define DI   2048
#define NEXP 24
#define TPG  2048
#define CAP  171
#define CAPR 176
#define EPSF 1e-6f

typedef __bf16 bf16x8 __attribute__((ext_vector_type(8)));
typedef float f32x4 __attribute__((ext_vector_type(4)));

static __device__ __forceinline__ unsigned short f2bf(float f) {
  unsigned int u = __builtin_bit_cast(unsigned int, f);
  u = (u + 0x7fffu + ((u >> 16) & 1u)) >> 16;
  return (unsigned short)u;
}
static __device__ __forceinline__ float bf2f(unsigned short u) {
  return __builtin_bit_cast(float, (unsigned int)u << 16);
}
static __device__ __forceinline__ unsigned int pk2(float a, float b) {
  return (unsigned int)f2bf(a) | ((unsigned int)f2bf(b) << 16);
}

// async global->LDS, 16B per lane; LDS dest is wave-uniform base + lane*16
static __device__ __forceinline__ void gload16(const unsigned short* g, unsigned short* l) {
  __builtin_amdgcn_global_load_lds(
      (const __attribute__((address_space(1))) void*)g,
      (__attribute__((address_space(3))) void*)l, 16, 0, 0);
}

// ---------------- weight transpose+convert: fp32 [e][K][N] -> bf16 [e][N][K]
__global__ __launch_bounds__(256) void convw(
    const float* __restrict__ in, unsigned short* __restrict__ out, int K, int N)
{
  __shared__ unsigned short T[64][65];
  int e = blockIdx.z;
  const float* ip = in + (size_t)e * K * N;
  unsigned short* op = out + (size_t)e * N * K;
  int n0 = blockIdx.x * 64, k0 = blockIdx.y * 64;
  int tid = threadIdx.x;
  #pragma unroll
  for (int i = 0; i < 16; ++i) {
    int lin = tid + i * 256;
    int k = lin >> 6, n = lin & 63;
    T[n][k] = f2bf(ip[(size_t)(k0 + k) * N + n0 + n]);
  }
  __syncthreads();
  #pragma unroll
  for (int i = 0; i < 16; ++i) {
    int lin = tid + i * 256;
    int n = lin >> 6, k = lin & 63;
    op[(size_t)(n0 + n) * K + k0 + k] = T[n][k];
  }
}

// ---------------- elementwise fp32 -> bf16
__global__ __launch_bounds__(256) void convx(
    const float* __restrict__ in, unsigned short* __restrict__ out)
{
  int i = blockIdx.x * 256 + threadIdx.x;
  float4 v = ((const float4*)in)[i];
  uint2 p;
  p.x = pk2(v.x, v.y); p.y = pk2(v.z, v.w);
  ((uint2*)out)[i] = p;
}

// ---------------- unified bf16-MFMA GEMM, 64m x 128n tile, BK=64, 4 waves
// single-buffered global_load_lds staging, XOR-swizzled LDS (24 KB -> 6 blocks/CU)
// A: bf16 rows [*, lda], optionally gathered via lrow (pair*CAPR+m)
// Bt: bf16 pre-transposed [e][N][K]
// mode 0: Cb[m*N+col] = bf16(acc * (col<512 ? scale : 1))          (fused QKV)
// mode 1: Cf[m*N+col] = relu(acc) + Add[m*N+col]
// mode 3: Cb[pair*CAPR*N + m*N + col] = bf16(acc + bias[e*N+col])  (per-slot MoE out)
__global__ __launch_bounds__(256) void mfma_gemm(
    const unsigned short* __restrict__ A, int lda,
    const unsigned short* __restrict__ Bt,
    const float* __restrict__ bias,
    const int* __restrict__ lrow, const int* __restrict__ cnts,
    float* __restrict__ Cf, unsigned short* __restrict__ Cb,
    const float* __restrict__ Add,
    int M, int N, int K, int mode, float scale)
{
  __shared__ unsigned short As[64 * 64];
  __shared__ unsigned short Bs[128 * 64];
  int tid = threadIdx.x;
  int w = tid >> 6, lane = tid & 63, quad = lane >> 4, l16 = lane & 15;
  int n0 = blockIdx.x * 128;
  int m0 = blockIdx.y * 64;
  int pair = blockIdx.z;
  int e = pair % NEXP;
  int count = cnts ? cnts[pair] : M;
  if (m0 >= count) return;
  const int* lr = lrow ? lrow + pair * CAPR : nullptr;

  int sub = lane >> 3;               // row-within-8-row wave chunk
  int gsw = (lane & 7) ^ sub;        // pre-swizzled source granule
  const unsigned short* aSrc[2];
  #pragma unroll
  for (int i = 0; i < 2; ++i) {
    int mm = m0 + i * 32 + w * 8 + sub;
    if (mm >= count) mm = count - 1;
    int rm = lr ? lr[mm] : mm;
    aSrc[i] = A + (size_t)rm * lda + gsw * 8;
  }
  const unsigned short* Bte = Bt + (size_t)e * N * K;
  const unsigned short* bSrc[4];
  #pragma unroll
  for (int i = 0; i < 4; ++i)
    bSrc[i] = Bte + (size_t)(n0 + i * 32 + w * 8 + sub) * K + gsw * 8;

  int wbase = w * 512;               // (w*8 rows) * 64 shorts

  f32x4 acc[4][2] = {};
  for (int t = 0; t < K; t += 64) {
    if (t) __syncthreads();          // previous tile fully consumed
    #pragma unroll
    for (int i = 0; i < 2; ++i) gload16(aSrc[i] + t, &As[i * 2048 + wbase]);
    #pragma unroll
    for (int i = 0; i < 4; ++i) gload16(bSrc[i] + t, &Bs[i * 2048 + wbase]);
    asm volatile("s_waitcnt vmcnt(0)" ::: "memory");
    __syncthreads();
    #pragma unroll
    for (int half = 0; half < 2; ++half) {
      int g8 = ((half * 4 + quad) ^ (l16 & 7)) * 8;   // swizzled read granule
      bf16x8 af[4];
      #pragma unroll
      for (int ms = 0; ms < 4; ++ms)
        af[ms] = *(const bf16x8*)&As[(ms * 16 + l16) * 64 + g8];
      bf16x8 bfr[2];
      #pragma unroll
      for (int ns = 0; ns < 2; ++ns)
        bfr[ns] = *(const bf16x8*)&Bs[(w * 32 + ns * 16 + l16) * 64 + g8];
      #pragma unroll
      for (int ms = 0; ms < 4; ++ms)
        #pragma unroll
        for (int ns = 0; ns < 2; ++ns)
          acc[ms][ns] = __builtin_amdgcn_mfma_f32_16x16x32_bf16(af[ms], bfr[ns], acc[ms][ns], 0, 0, 0);
    }
  }
  // ---- epilogue
  float bv[2] = {0.f, 0.f};
  unsigned short* Cbp = Cb;
  if (mode == 3) {
    #pragma unroll
    for (int ns = 0; ns < 2; ++ns)
      bv[ns] = bias[(size_t)e * N + n0 + w * 32 + ns * 16 + l16];
    Cbp = Cb + (size_t)pair * CAPR * N;
  }
  #pragma unroll
  for (int ms = 0; ms < 4; ++ms) {
    #pragma unroll
    for (int ns = 0; ns < 2; ++ns) {
      int col = n0 + w * 32 + ns * 16 + l16;
      #pragma unroll
      for (int r = 0; r < 4; ++r) {
        int m = m0 + ms * 16 + quad * 4 + r;
        if (mode == 0) {
          float sc = col < 512 ? scale : 1.0f;
          Cbp[(size_t)m * N + col] = f2bf(acc[ms][ns][r] * sc);
        } else if (mode == 1) {
          Cf[(size_t)m * N + col] = fmaxf(acc[ms][ns][r], 0.f) + Add[(size_t)m * N + col];
        } else {
          if (m < CAPR)
            Cbp[(size_t)m * N + col] = f2bf(acc[ms][ns][r] + bv[ns]);
        }
      }
    }
  }
}

// ---------------- MFMA bf16 flash attention; QKV packed [tok][1536], ctx bf16 [tok][512]
__global__ __launch_bounds__(256) void attn_mfma(
    const unsigned short* __restrict__ QKV, unsigned short* __restrict__ ctx)
{
  __shared__ unsigned short Ks[64 * 72];
  __shared__ unsigned short Vt[64 * 72];
  __shared__ unsigned short Ps[4][16 * 72];
  int tid = threadIdx.x;
  int w = tid >> 6, lane = tid & 63, quad = lane >> 4, l16 = lane & 15;
  int qt = blockIdx.x, bh = blockIdx.y;
  int b = bh >> 3, h = bh & 7;
  size_t hoff = (size_t)h * 64;
  size_t tokbase = (size_t)b * 1024;

  int qrow = qt * 64 + w * 16 + l16;
  const unsigned short* qp = QKV + (tokbase + qrow) * 1536 + hoff + quad * 8;
  bf16x8 qa0 = *(const bf16x8*)(qp);
  bf16x8 qa1 = *(const bf16x8*)(qp + 32);

  f32x4 O[4] = {};
  float mrow[4], lrowv[4];
  #pragma unroll
  for (int r = 0; r < 4; ++r) { mrow[r] = -1e30f; lrowv[r] = 0.f; }

  for (int kv0 = 0; kv0 < 1024; kv0 += 64) {
    __syncthreads();
    {
      const unsigned short* kg = QKV + (tokbase + kv0) * 1536 + 512 + hoff;
      #pragma unroll
      for (int i = 0; i < 2; ++i) {
        int f = tid + i * 256;
        int key = f >> 3, c = f & 7;
        *(uint4*)&Ks[key * 72 + c * 8] = *(const uint4*)(kg + (size_t)key * 1536 + c * 8);
      }
      const unsigned short* vg = QKV + (tokbase + kv0) * 1536 + 1024 + hoff;
      int d = tid & 63;
      #pragma unroll
      for (int i = 0; i < 2; ++i) {
        int ko = (tid >> 6) + i * 4;
        const unsigned short* vq = vg + (size_t)ko * 8 * 1536 + d;
        unsigned int a0 = vq[0],         a1 = vq[1536];
        unsigned int a2 = vq[2 * 1536],  a3 = vq[3 * 1536];
        unsigned int a4 = vq[4 * 1536],  a5 = vq[5 * 1536];
        unsigned int a6 = vq[6 * 1536],  a7 = vq[7 * 1536];
        uint4 pk;
        pk.x = a0 | (a1 << 16); pk.y = a2 | (a3 << 16);
        pk.z = a4 | (a5 << 16); pk.w = a6 | (a7 << 16);
        *(uint4*)&Vt[d * 72 + ko * 8] = pk;
      }
    }
    __syncthreads();

    f32x4 s[4];
    #pragma unroll
    for (int kt = 0; kt < 4; ++kt) {
      const unsigned short* kr = &Ks[(kt * 16 + l16) * 72 + quad * 8];
      bf16x8 kb0 = *(const bf16x8*)(kr);
      bf16x8 kb1 = *(const bf16x8*)(kr + 32);
      f32x4 z = {};
      z = __builtin_amdgcn_mfma_f32_16x16x32_bf16(qa0, kb0, z, 0, 0, 0);
      z = __builtin_amdgcn_mfma_f32_16x16x32_bf16(qa1, kb1, z, 0, 0, 0);
      s[kt] = z;
    }

    #pragma unroll
    for (int r = 0; r < 4; ++r) {
      float mx = fmaxf(fmaxf(s[0][r], s[1][r]), fmaxf(s[2][r], s[3][r]));
      mx = fmaxf(mx, __shfl_xor(mx, 1, 64));
      mx = fmaxf(mx, __shfl_xor(mx, 2, 64));
      mx = fmaxf(mx, __shfl_xor(mx, 4, 64));
      mx = fmaxf(mx, __shfl_xor(mx, 8, 64));
      float mnew = fmaxf(mrow[r], mx);
      float alpha = __expf(mrow[r] - mnew);
      mrow[r] = mnew;
      float psum = 0.f;
      #pragma unroll
      for (int kt = 0; kt < 4; ++kt) {
        float p = __expf(s[kt][r] - mnew);
        s[kt][r] = p;
        psum += p;
      }
      psum += __shfl_xor(psum, 1, 64);
      psum += __shfl_xor(psum, 2, 64);
      psum += __shfl_xor(psum, 4, 64);
      psum += __shfl_xor(psum, 8, 64);
      lrowv[r] = lrowv[r] * alpha + psum;
      #pragma unroll
      for (int dt = 0; dt < 4; ++dt) O[dt][r] *= alpha;
    }

    #pragma unroll
    for (int kt = 0; kt < 4; ++kt)
      #pragma unroll
      for (int r = 0; r < 4; ++r)
        Ps[w][(quad * 4 + r) * 72 + kt * 16 + l16] = f2bf(s[kt][r]);
    const unsigned short* pp = &Ps[w][l16 * 72 + quad * 8];
    bf16x8 pa0 = *(const bf16x8*)(pp);
    bf16x8 pa1 = *(const bf16x8*)(pp + 32);

    #pragma unroll
    for (int dt = 0; dt < 4; ++dt) {
      const unsigned short* vr = &Vt[(dt * 16 + l16) * 72 + quad * 8];
      bf16x8 vb0 = *(const bf16x8*)(vr);
      bf16x8 vb1 = *(const bf16x8*)(vr + 32);
      O[dt] = __builtin_amdgcn_mfma_f32_16x16x32_bf16(pa0, vb0, O[dt], 0, 0, 0);
      O[dt] = __builtin_amdgcn_mfma_f32_16x16x32_bf16(pa1, vb1, O[dt], 0, 0, 0);
    }
  }

  #pragma unroll
  for (int r = 0; r < 4; ++r) {
    float inv = 1.0f / lrowv[r];
    int row = qt * 64 + w * 16 + quad * 4 + r;
    unsigned short* cp = ctx + (tokbase + row) * 512 + hoff + l16;
    #pragma unroll
    for (int dt = 0; dt < 4; ++dt) cp[dt * 16] = f2bf(O[dt][r] * inv);
  }
}

// ---------------- layernorm (fp32 in, optional dual fp32/bf16 out)
__global__ __launch_bounds__(256) void ln_kernel(
    const float* __restrict__ in,
    float* __restrict__ out, unsigned short* __restrict__ outb,
    int D, const float* __restrict__ g, const float* __restrict__ bb)
{
  int row = blockIdx.x;
  const float* ip = in + (size_t)row * D;
  float vals[8];
  int per = D >> 8;
  float s1 = 0.f, s2 = 0.f;
  for (int i = 0; i < per; ++i) {
    int d = threadIdx.x + (i << 8);
    float vv = ip[d];
    vals[i] = vv; s1 += vv; s2 += vv * vv;
  }
  #pragma unroll
  for (int o = 32; o; o >>= 1) { s1 += __shfl_xor(s1, o, 64); s2 += __shfl_xor(s2, o, 64); }
  __shared__ float sA[4], sB[4];
  int wid = threadIdx.x >> 6, lane = threadIdx.x & 63;
  if (lane == 0) { sA[wid] = s1; sB[wid] = s2; }
  __syncthreads();
  float t1 = sA[0] + sA[1] + sA[2] + sA[3];
  float t2 = sB[0] + sB[1] + sB[2] + sB[3];
  float mean = t1 / (float)D;
  float var = t2 / (float)D - mean * mean;
  float rs = rsqrtf(var + EPSF);
  float* op = out ? out + (size_t)row * D : nullptr;
  unsigned short* obp = outb ? outb + (size_t)row * D : nullptr;
  for (int i = 0; i < per; ++i) {
    int d = threadIdx.x + (i << 8);
    float o = (vals[i] - mean) * rs * g[d] + bb[d];
    if (op)  op[d] = o;
    if (obp) obp[d] = f2bf(o);
  }
}

// ---------------- combine (<=2 expert slots) + optional add + LN (+relu) -> bf16/fp32
template<int PER>
__global__ __launch_bounds__(256) void combine_ln(
    const unsigned short* __restrict__ slots,
    const int* __restrict__ ts0, const int* __restrict__ ts1,
    const float* __restrict__ sw,
    const float* __restrict__ addf,
    float* __restrict__ outf, unsigned short* __restrict__ outb,
    int relu_after,
    const float* __restrict__ g0, const float* __restrict__ g1,
    const float* __restrict__ g2, const float* __restrict__ g3,
    const float* __restrict__ bb0, const float* __restrict__ bb1,
    const float* __restrict__ bb2, const float* __restrict__ bb3)
{
  const int D = PER * 256;
  int row = blockIdx.x;
  int grp = (row & 1023) >> 8;
  const float* g  = grp == 0 ? g0  : grp == 1 ? g1  : grp == 2 ? g2  : g3;
  const float* bb = grp == 0 ? bb0 : grp == 1 ? bb1 : grp == 2 ? bb2 : bb3;
  int s0 = ts0[row], s1 = ts1[row];
  float w0 = s0 >= 0 ? sw[s0] : 0.f;
  float w1 = s1 >= 0 ? sw[s1] : 0.f;
  const unsigned short* p0 = slots + (size_t)(s0 >= 0 ? s0 : 0) * D;
  const unsigned short* p1 = slots + (size_t)(s1 >= 0 ? s1 : 0) * D;
  const float* ap = addf ? addf + (size_t)row * D : nullptr;
  int base = threadIdx.x * PER;
  float vals[PER];
  float sm1 = 0.f, sm2 = 0.f;
  #pragma unroll
  for (int i = 0; i < PER; ++i) {
    int d = base + i;
    float v = ap ? ap[d] : 0.f;
    if (s0 >= 0) v += w0 * bf2f(p0[d]);
    if (s1 >= 0) v += w1 * bf2f(p1[d]);
    vals[i] = v; sm1 += v; sm2 += v * v;
  }
  #pragma unroll
  for (int o = 32; o; o >>= 1) { sm1 += __shfl_xor(sm1, o, 64); sm2 += __shfl_xor(sm2, o, 64); }
  __shared__ float sA[4], sB[4];
  int wid = threadIdx.x >> 6, lane = threadIdx.x & 63;
  if (lane == 0) { sA[wid] = sm1; sB[wid] = sm2; }
  __syncthreads();
  float t1 = sA[0] + sA[1] + sA[2] + sA[3];
  float t2 = sB[0] + sB[1] + sB[2] + sB[3];
  float mean = t1 / (float)D;
  float var = t2 / (float)D - mean * mean;
  float rs = rsqrtf(var + EPSF);
  float* op = outf ? outf + (size_t)row * D : nullptr;
  unsigned short* obp = outb ? outb + (size_t)row * D : nullptr;
  #pragma unroll
  for (int i = 0; i < PER; ++i) {
    int d = base + i;
    float o = (vals[i] - mean) * rs * g[d] + bb[d];
    if (relu_after) o = fmaxf(o, 0.f);
    if (op)  op[d] = o;
    if (obp) obp[d] = f2bf(o);
  }
}

// ---------------- gating stage 1
__global__ __launch_bounds__(256) void gate1(
    const float* __restrict__ xln, const float* __restrict__ wg,
    int* __restrict__ idx0, int* __restrict__ idx1,
    float* __restrict__ w0o, float* __restrict__ w1o)
{
  int wid = threadIdx.x >> 6, lane = threadIdx.x & 63;
  int tk = blockIdx.x * 4 + wid;
  int g = tk >> 11, t = tk & 2047;
  int b = t >> 8, j = t & 255;
  size_t row = (size_t)b * 1024 + g * 256 + j;
  const float* xp = xln + row * 512;
  float acc = -1e30f;
  if (lane < 24) {
    acc = 0.f;
    for (int d = 0; d < 512; ++d) acc += xp[d] * wg[d * 24 + lane];
  }
  float b0v = -1e30f, b1v = -1e30f; int i0 = 0, i1 = 0;
  for (int e = 0; e < 24; ++e) {
    float vv = __shfl(acc, e, 64);
    if (vv > b0v)      { b1v = b0v; i1 = i0; b0v = vv; i0 = e; }
    else if (vv > b1v) { b1v = vv; i1 = e; }
  }
  if (lane == 0) {
    float w0 = 1.0f / (1.0f + __expf(b1v - b0v));
    idx0[tk] = i0; idx1[tk] = i1; w0o[tk] = w0; w1o[tk] = 1.0f - w0;
  }
}

// ---------------- gating stage 2 (adds inverse token->slot maps ts0/ts1)
__global__ __launch_bounds__(64) void gate2(
    const int* __restrict__ idx0, const int* __restrict__ idx1,
    const float* __restrict__ w0, const float* __restrict__ w1,
    int* __restrict__ lrow, float* __restrict__ lw, int* __restrict__ counts,
    int* __restrict__ ts0, int* __restrict__ ts1)
{
  int pair = blockIdx.x; int g = pair / 24; int e = pair % 24;
  int lane = threadIdx.x;
  int base = g * TPG;
  unsigned long long lm = (lane == 63) ? 0x7fffffffffffffffULL : ((1ULL << lane) - 1ULL);
  int run = 0;
  for (int it = 0; it < TPG / 64; ++it) {
    int t = it * 64 + lane;
    bool m = (idx0[base + t] == e);
    unsigned long long mask = __ballot(m);
    int pre = __popcll(mask & lm);
    int rank = run + pre;
    if (m && rank < CAP) {
      int bq = t >> 8, j = t & 255;
      int rowidx = bq * 1024 + g * 256 + j;
      lrow[pair * CAPR + rank] = rowidx;
      lw[pair * CAPR + rank] = w0[base + t];
      ts0[rowidx] = pair * CAPR + rank;
    }
    run += __popcll(mask);
  }
  int total1 = run;
  int run2 = 0;
  for (int it = 0; it < TPG / 64; ++it) {
    int t = it * 64 + lane;
    bool m = (idx1[base + t] == e);
    unsigned long long mask = __ballot(m);
    int pre = __popcll(mask & lm);
    int rank2 = run2 + pre;
    if (m && (total1 + rank2) < CAP) {
      int bq = t >> 8, j = t & 255;
      int rowidx = bq * 1024 + g * 256 + j;
      lrow[pair * CAPR + total1 + rank2] = rowidx;
      lw[pair * CAPR + total1 + rank2] = w1[base + t];
      ts1[rowidx] = pair * CAPR + total1 + rank2;
    }
    run2 += __popcll(mask);
  }
  if (lane == 0) {
    int c1 = total1 < CAP ? total1 : CAP;
    int room = CAP - total1; if (room < 0) room = 0;
    int c2 = run2 < room ? run2 : room;
    counts[pair] = c1 + c2;
  }
}

extern "C" void kernel_launch(void* const* d_in, const int* in_sizes, int n_in,
                              void* d_out, int out_size, void* d_ws, size_t ws_size,
                              hipStream_t stream)
{
  const float* x   = (const float*)d_in[0];
  const float* wq  = (const float*)d_in[1];
  const float* wk  = (const float*)d_in[2];
  const float* wv  = (const float*)d_in[3];
  const float* wo  = (const float*)d_in[4];
  const float* ln_attn_g = (const float*)d_in[5];
  const float* ln_attn_b = (const float*)d_in[6];
  const float* wg1 = (const float*)d_in[7];
  const float* w1  = (const float*)d_in[8];
  const float* b1  = (const float*)d_in[9];
  const float* w2  = (const float*)d_in[11];
  const float* b2  = (const float*)d_in[12];
  const float* ln_out_g = (const float*)d_in[13];
  const float* ln_out_b = (const float*)d_in[14];
  const float* ln1g = (const float*)d_in[15]; const float* ln1b = (const float*)d_in[16];
  const float* ln2g = (const float*)d_in[17]; const float* ln2b = (const float*)d_in[18];
  const float* ln3g = (const float*)d_in[19]; const float* ln3b = (const float*)d_in[20];
  const float* ln4g = (const float*)d_in[21]; const float* ln4b = (const float*)d_in[22];

  char* ws = (char*)d_ws;
  const size_t MB = 1048576;
  unsigned short* wt1    = (unsigned short*)(ws + 0);
  unsigned short* hb2    = (unsigned short*)(ws + 0);            // after MoE1
  unsigned short* wt2    = (unsigned short*)(ws + 48 * MB);
  float*          ctxln  = (float*)(ws + 96 * MB);
  unsigned short* ctxlnb = (unsigned short*)(ws + 112 * MB);
  unsigned short* xbf    = (unsigned short*)(ws + 120 * MB);
  unsigned short* out1   = (unsigned short*)(ws + 120 * MB);     // after attn chain
  unsigned short* out2   = (unsigned short*)(ws + 120 * MB);     // after combine1
  unsigned short* qkvb   = (unsigned short*)(ws + 128 * MB);
  unsigned short* ctxb   = (unsigned short*)(ws + 152 * MB);
  unsigned short* wtqkv  = (unsigned short*)(ws + 160 * MB);
  unsigned short* wto    = (unsigned short*)(ws + 160 * MB + 1572864);
  float*          y0     = (float*)(ws + 162 * MB);
  char*  small = ws + 190 * MB;
  int*   idx0  = (int*)(small + 0);
  int*   idx1  = (int*)(small + 32768);
  float* w0a   = (float*)(small + 65536);
  float* w1a   = (float*)(small + 98304);
  int*   lrowp = (int*)(small + 131072);
  float* lwv   = (float*)(small + 198656);
  int*   cnts  = (int*)(small + 266240);
  int*   ts0   = (int*)(small + 270336);
  int*   ts1   = (int*)(small + 303104);

  dim3 blk(256);
  // ---- one-time conversions (bf16, B pre-transposed to [n][k]); qkv packed [1536][512]
  convw<<<dim3(8, 8, 1), blk, 0, stream>>>(wq, wtqkv, 512, 512);
  convw<<<dim3(8, 8, 1), blk, 0, stream>>>(wk, wtqkv + (size_t)512 * 512, 512, 512);
  convw<<<dim3(8, 8, 1), blk, 0, stream>>>(wv, wtqkv + (size_t)1024 * 512, 512, 512);
  convw<<<dim3(8, 8, 1), blk, 0, stream>>>(wo, wto, 512, 512);
  convw<<<dim3(32, 8, 24), blk, 0, stream>>>(w1, wt1, 512, 2048);
  convw<<<dim3(8, 32, 24), blk, 0, stream>>>(w2, wt2, 2048, 512);
  convx<<<4096, blk, 0, stream>>>(x, xbf);
  // ---- fused QKV projection (q scaled by 1/8 via per-col scale)
  mfma_gemm<<<dim3(12, 128, 1), blk, 0, stream>>>(xbf, DM, wtqkv, nullptr, nullptr, nullptr,
      nullptr, qkvb, nullptr, NTOK, 1536, DM, 0, 0.125f);
  // ---- attention
  attn_mfma<<<dim3(16, 64), blk, 0, stream>>>(qkvb, ctxb);
  // ---- y0 = relu(ctx@wo) + x
  mfma_gemm<<<dim3(4, 128, 1), blk, 0, stream>>>(ctxb, DM, wto, nullptr, nullptr, nullptr,
      y0, nullptr, x, NTOK, DM, DM, 1, 1.0f);
  // ---- ctx_ln = LN(y0), fp32 + bf16
  ln_kernel<<<8192, blk, 0, stream>>>(y0, ctxln, ctxlnb, DM, ln_attn_g, ln_attn_b);
  // ---- gating
  gate1<<<2048, blk, 0, stream>>>(ctxln, wg1, idx0, idx1, w0a, w1a);
  hipMemsetAsync(ts0, 0xFF, 65536, stream);      // ts0+ts1 = -1
  gate2<<<96, 64, 0, stream>>>(idx0, idx1, w0a, w1a, lrowp, lwv, cnts, ts0, ts1);
  // ---- MoE layer 1: per-slot out1[pair][CAPR][DI] = bf16(ctxln@W1[e] + b1[e])
  mfma_gemm<<<dim3(16, 3, 96), blk, 0, stream>>>(ctxlnb, DM, wt1, b1, lrowp, cnts,
      nullptr, out1, nullptr, 0, DI, DM, 3, 1.0f);
  // ---- hb2 = bf16(relu(LN_g(combine(out1))))
  combine_ln<8><<<8192, blk, 0, stream>>>(out1, ts0, ts1, lwv, nullptr,
      nullptr, hb2, 1, ln1g, ln2g, ln3g, ln4g, ln1b, ln2b, ln3b, ln4b);
  // ---- MoE layer 2: per-slot out2[pair][CAPR][DM] = bf16(hb2@W2[e] + b2[e])
  mfma_gemm<<<dim3(4, 3, 96), blk, 0, stream>>>(hb2, DI, wt2, b2, lrowp, cnts,
      nullptr, out2, nullptr, 0, DM, DI, 3, 1.0f);
  // ---- out = LN(combine(out2) + ctxln)
  combine_ln<2><<<8192, blk, 0, stream>>>(out2, ts0, ts1, lwv, ctxln,
      (float*)d_out, nullptr, 0, ln_out_g, ln_out_g, ln_out_g, ln_out_g,
      ln_out_b, ln_out_b, ln_out_b, ln_out_b);
}

// Round 4
// 699.258 us; speedup vs baseline: 1.1867x; 1.1103x over previous
//
#include <hip/hip_runtime.h>
#include <cstdint>

// ws layout (bytes, MB = 2^20):
// [0,48)    wt1 bf16 [24][2048][512]   : conv .. MoE1      } hb2 bf16 [0,32) : combine1 .. MoE2
// [48,96)   wt2 bf16 [24][512][2048]   : conv .. MoE2
// [96,112)  ctxln fp32                 : ctxLN .. final
// [112,120) ctxlnb bf16                : ctxLN .. MoE1
// [120,..)  early: xbf[120,128) qkvb[128,152) ctxb[152,160) wtqkv[160,161.5) wto[161.5,162) y0[162,178)
//           then: out1 bf16 [120,189.3) : MoE1 .. combine1 ; then out2 bf16 [120,137.3) : MoE2 .. final
// [190,..)  small gating buffers + ts0/ts1

#define NTOK 8192
#define DM   512
#define DI   2048
#define NEXP 24
#define TPG  2048
#define CAP  171
#define CAPR 176
#define EPSF 1e-6f

typedef __bf16 bf16x8 __attribute__((ext_vector_type(8)));
typedef float f32x4 __attribute__((ext_vector_type(4)));

static __device__ __forceinline__ unsigned short f2bf(float f) {
  unsigned int u = __builtin_bit_cast(unsigned int, f);
  u = (u + 0x7fffu + ((u >> 16) & 1u)) >> 16;
  return (unsigned short)u;
}
static __device__ __forceinline__ float bf2f(unsigned short u) {
  return __builtin_bit_cast(float, (unsigned int)u << 16);
}
static __device__ __forceinline__ unsigned int pk2(float a, float b) {
  return (unsigned int)f2bf(a) | ((unsigned int)f2bf(b) << 16);
}

// async global->LDS, 16B per lane; LDS dest is wave-uniform base + lane*16
static __device__ __forceinline__ void gload16(const unsigned short* g, unsigned short* l) {
  __builtin_amdgcn_global_load_lds(
      (const __attribute__((address_space(1))) void*)g,
      (__attribute__((address_space(3))) void*)l, 16, 0, 0);
}

// ---------------- weight transpose+convert: fp32 [e][K][N] -> bf16 [e][N][K]
__global__ __launch_bounds__(256) void convw(
    const float* __restrict__ in, unsigned short* __restrict__ out, int K, int N)
{
  __shared__ unsigned short T[64][65];
  int e = blockIdx.z;
  const float* ip = in + (size_t)e * K * N;
  unsigned short* op = out + (size_t)e * N * K;
  int n0 = blockIdx.x * 64, k0 = blockIdx.y * 64;
  int tid = threadIdx.x;
  #pragma unroll
  for (int i = 0; i < 16; ++i) {
    int lin = tid + i * 256;
    int k = lin >> 6, n = lin & 63;
    T[n][k] = f2bf(ip[(size_t)(k0 + k) * N + n0 + n]);
  }
  __syncthreads();
  #pragma unroll
  for (int i = 0; i < 16; ++i) {
    int lin = tid + i * 256;
    int n = lin >> 6, k = lin & 63;
    op[(size_t)(n0 + n) * K + k0 + k] = T[n][k];
  }
}

// ---------------- elementwise fp32 -> bf16
__global__ __launch_bounds__(256) void convx(
    const float* __restrict__ in, unsigned short* __restrict__ out)
{
  int i = blockIdx.x * 256 + threadIdx.x;
  float4 v = ((const float4*)in)[i];
  uint2 p;
  p.x = pk2(v.x, v.y); p.y = pk2(v.z, v.w);
  ((uint2*)out)[i] = p;
}

// ---------------- unified bf16-MFMA GEMM, 64m x 128n tile, BK=64, 4 waves
// single-buffered global_load_lds staging, XOR-swizzled LDS (24 KB -> 6 blocks/CU)
// A: bf16 rows [*, lda], optionally gathered via lrow (pair*CAPR+m)
// Bt: bf16 pre-transposed [e][N][K]
// mode 0: Cb[m*N+col] = bf16(acc * (col<512 ? scale : 1))          (fused QKV)
// mode 1: Cf[m*N+col] = relu(acc) + Add[m*N+col]
// mode 3: Cb[pair*CAPR*N + m*N + col] = bf16(acc + bias[e*N+col])  (per-slot MoE out)
__global__ __launch_bounds__(256) void mfma_gemm(
    const unsigned short* __restrict__ A, int lda,
    const unsigned short* __restrict__ Bt,
    const float* __restrict__ bias,
    const int* __restrict__ lrow, const int* __restrict__ cnts,
    float* __restrict__ Cf, unsigned short* __restrict__ Cb,
    const float* __restrict__ Add,
    int M, int N, int K, int mode, float scale)
{
  __shared__ unsigned short As[64 * 64];
  __shared__ unsigned short Bs[128 * 64];
  int tid = threadIdx.x;
  int w = tid >> 6, lane = tid & 63, quad = lane >> 4, l16 = lane & 15;
  int n0 = blockIdx.x * 128;
  int m0 = blockIdx.y * 64;
  int pair = blockIdx.z;
  int e = pair % NEXP;
  int count = cnts ? cnts[pair] : M;
  if (m0 >= count) return;
  const int* lr = lrow ? lrow + pair * CAPR : nullptr;

  int sub = lane >> 3;               // row-within-8-row wave chunk
  int gsw = (lane & 7) ^ sub;        // pre-swizzled source granule
  const unsigned short* aSrc[2];
  #pragma unroll
  for (int i = 0; i < 2; ++i) {
    int mm = m0 + i * 32 + w * 8 + sub;
    if (mm >= count) mm = count - 1;
    int rm = lr ? lr[mm] : mm;
    aSrc[i] = A + (size_t)rm * lda + gsw * 8;
  }
  const unsigned short* Bte = Bt + (size_t)e * N * K;
  const unsigned short* bSrc[4];
  #pragma unroll
  for (int i = 0; i < 4; ++i)
    bSrc[i] = Bte + (size_t)(n0 + i * 32 + w * 8 + sub) * K + gsw * 8;

  int wbase = w * 512;               // (w*8 rows) * 64 shorts

  f32x4 acc[4][2] = {};
  for (int t = 0; t < K; t += 64) {
    if (t) __syncthreads();          // previous tile fully consumed
    #pragma unroll
    for (int i = 0; i < 2; ++i) gload16(aSrc[i] + t, &As[i * 2048 + wbase]);
    #pragma unroll
    for (int i = 0; i < 4; ++i) gload16(bSrc[i] + t, &Bs[i * 2048 + wbase]);
    asm volatile("s_waitcnt vmcnt(0)" ::: "memory");
    __syncthreads();
    #pragma unroll
    for (int half = 0; half < 2; ++half) {
      int g8 = ((half * 4 + quad) ^ (l16 & 7)) * 8;   // swizzled read granule
      bf16x8 af[4];
      #pragma unroll
      for (int ms = 0; ms < 4; ++ms)
        af[ms] = *(const bf16x8*)&As[(ms * 16 + l16) * 64 + g8];
      bf16x8 bfr[2];
      #pragma unroll
      for (int ns = 0; ns < 2; ++ns)
        bfr[ns] = *(const bf16x8*)&Bs[(w * 32 + ns * 16 + l16) * 64 + g8];
      #pragma unroll
      for (int ms = 0; ms < 4; ++ms)
        #pragma unroll
        for (int ns = 0; ns < 2; ++ns)
          acc[ms][ns] = __builtin_amdgcn_mfma_f32_16x16x32_bf16(af[ms], bfr[ns], acc[ms][ns], 0, 0, 0);
    }
  }
  // ---- epilogue
  float bv[2] = {0.f, 0.f};
  unsigned short* Cbp = Cb;
  if (mode == 3) {
    #pragma unroll
    for (int ns = 0; ns < 2; ++ns)
      bv[ns] = bias[(size_t)e * N + n0 + w * 32 + ns * 16 + l16];
    Cbp = Cb + (size_t)pair * CAPR * N;
  }
  #pragma unroll
  for (int ms = 0; ms < 4; ++ms) {
    #pragma unroll
    for (int ns = 0; ns < 2; ++ns) {
      int col = n0 + w * 32 + ns * 16 + l16;
      #pragma unroll
      for (int r = 0; r < 4; ++r) {
        int m = m0 + ms * 16 + quad * 4 + r;
        if (mode == 0) {
          float sc = col < 512 ? scale : 1.0f;
          Cbp[(size_t)m * N + col] = f2bf(acc[ms][ns][r] * sc);
        } else if (mode == 1) {
          Cf[(size_t)m * N + col] = fmaxf(acc[ms][ns][r], 0.f) + Add[(size_t)m * N + col];
        } else {
          if (m < CAPR)
            Cbp[(size_t)m * N + col] = f2bf(acc[ms][ns][r] + bv[ns]);
        }
      }
    }
  }
}

// ---------------- MFMA bf16 flash attention; QKV packed [tok][1536], ctx bf16 [tok][512]
__global__ __launch_bounds__(256) void attn_mfma(
    const unsigned short* __restrict__ QKV, unsigned short* __restrict__ ctx)
{
  __shared__ unsigned short Ks[64 * 72];
  __shared__ unsigned short Vt[64 * 72];
  __shared__ unsigned short Ps[4][16 * 72];
  int tid = threadIdx.x;
  int w = tid >> 6, lane = tid & 63, quad = lane >> 4, l16 = lane & 15;
  int qt = blockIdx.x, bh = blockIdx.y;
  int b = bh >> 3, h = bh & 7;
  size_t hoff = (size_t)h * 64;
  size_t tokbase = (size_t)b * 1024;

  int qrow = qt * 64 + w * 16 + l16;
  const unsigned short* qp = QKV + (tokbase + qrow) * 1536 + hoff + quad * 8;
  bf16x8 qa0 = *(const bf16x8*)(qp);
  bf16x8 qa1 = *(const bf16x8*)(qp + 32);

  f32x4 O[4] = {};
  float mrow[4], lrowv[4];
  #pragma unroll
  for (int r = 0; r < 4; ++r) { mrow[r] = -1e30f; lrowv[r] = 0.f; }

  for (int kv0 = 0; kv0 < 1024; kv0 += 64) {
    __syncthreads();
    {
      const unsigned short* kg = QKV + (tokbase + kv0) * 1536 + 512 + hoff;
      #pragma unroll
      for (int i = 0; i < 2; ++i) {
        int f = tid + i * 256;
        int key = f >> 3, c = f & 7;
        *(uint4*)&Ks[key * 72 + c * 8] = *(const uint4*)(kg + (size_t)key * 1536 + c * 8);
      }
      const unsigned short* vg = QKV + (tokbase + kv0) * 1536 + 1024 + hoff;
      int d = tid & 63;
      #pragma unroll
      for (int i = 0; i < 2; ++i) {
        int ko = (tid >> 6) + i * 4;
        const unsigned short* vq = vg + (size_t)ko * 8 * 1536 + d;
        unsigned int a0 = vq[0],         a1 = vq[1536];
        unsigned int a2 = vq[2 * 1536],  a3 = vq[3 * 1536];
        unsigned int a4 = vq[4 * 1536],  a5 = vq[5 * 1536];
        unsigned int a6 = vq[6 * 1536],  a7 = vq[7 * 1536];
        uint4 pk;
        pk.x = a0 | (a1 << 16); pk.y = a2 | (a3 << 16);
        pk.z = a4 | (a5 << 16); pk.w = a6 | (a7 << 16);
        *(uint4*)&Vt[d * 72 + ko * 8] = pk;
      }
    }
    __syncthreads();

    f32x4 s[4];
    #pragma unroll
    for (int kt = 0; kt < 4; ++kt) {
      const unsigned short* kr = &Ks[(kt * 16 + l16) * 72 + quad * 8];
      bf16x8 kb0 = *(const bf16x8*)(kr);
      bf16x8 kb1 = *(const bf16x8*)(kr + 32);
      f32x4 z = {};
      z = __builtin_amdgcn_mfma_f32_16x16x32_bf16(qa0, kb0, z, 0, 0, 0);
      z = __builtin_amdgcn_mfma_f32_16x16x32_bf16(qa1, kb1, z, 0, 0, 0);
      s[kt] = z;
    }

    #pragma unroll
    for (int r = 0; r < 4; ++r) {
      float mx = fmaxf(fmaxf(s[0][r], s[1][r]), fmaxf(s[2][r], s[3][r]));
      mx = fmaxf(mx, __shfl_xor(mx, 1, 64));
      mx = fmaxf(mx, __shfl_xor(mx, 2, 64));
      mx = fmaxf(mx, __shfl_xor(mx, 4, 64));
      mx = fmaxf(mx, __shfl_xor(mx, 8, 64));
      float mnew = fmaxf(mrow[r], mx);
      float alpha = __expf(mrow[r] - mnew);
      mrow[r] = mnew;
      float psum = 0.f;
      #pragma unroll
      for (int kt = 0; kt < 4; ++kt) {
        float p = __expf(s[kt][r] - mnew);
        s[kt][r] = p;
        psum += p;
      }
      psum += __shfl_xor(psum, 1, 64);
      psum += __shfl_xor(psum, 2, 64);
      psum += __shfl_xor(psum, 4, 64);
      psum += __shfl_xor(psum, 8, 64);
      lrowv[r] = lrowv[r] * alpha + psum;
      #pragma unroll
      for (int dt = 0; dt < 4; ++dt) O[dt][r] *= alpha;
    }

    #pragma unroll
    for (int kt = 0; kt < 4; ++kt)
      #pragma unroll
      for (int r = 0; r < 4; ++r)
        Ps[w][(quad * 4 + r) * 72 + kt * 16 + l16] = f2bf(s[kt][r]);
    const unsigned short* pp = &Ps[w][l16 * 72 + quad * 8];
    bf16x8 pa0 = *(const bf16x8*)(pp);
    bf16x8 pa1 = *(const bf16x8*)(pp + 32);

    #pragma unroll
    for (int dt = 0; dt < 4; ++dt) {
      const unsigned short* vr = &Vt[(dt * 16 + l16) * 72 + quad * 8];
      bf16x8 vb0 = *(const bf16x8*)(vr);
      bf16x8 vb1 = *(const bf16x8*)(vr + 32);
      O[dt] = __builtin_amdgcn_mfma_f32_16x16x32_bf16(pa0, vb0, O[dt], 0, 0, 0);
      O[dt] = __builtin_amdgcn_mfma_f32_16x16x32_bf16(pa1, vb1, O[dt], 0, 0, 0);
    }
  }

  #pragma unroll
  for (int r = 0; r < 4; ++r) {
    float inv = 1.0f / lrowv[r];
    int row = qt * 64 + w * 16 + quad * 4 + r;
    unsigned short* cp = ctx + (tokbase + row) * 512 + hoff + l16;
    #pragma unroll
    for (int dt = 0; dt < 4; ++dt) cp[dt * 16] = f2bf(O[dt][r] * inv);
  }
}

// ---------------- layernorm (fp32 in, optional dual fp32/bf16 out)
__global__ __launch_bounds__(256) void ln_kernel(
    const float* __restrict__ in,
    float* __restrict__ out, unsigned short* __restrict__ outb,
    int D, const float* __restrict__ g, const float* __restrict__ bb)
{
  int row = blockIdx.x;
  const float* ip = in + (size_t)row * D;
  float vals[8];
  int per = D >> 8;
  float s1 = 0.f, s2 = 0.f;
  for (int i = 0; i < per; ++i) {
    int d = threadIdx.x + (i << 8);
    float vv = ip[d];
    vals[i] = vv; s1 += vv; s2 += vv * vv;
  }
  #pragma unroll
  for (int o = 32; o; o >>= 1) { s1 += __shfl_xor(s1, o, 64); s2 += __shfl_xor(s2, o, 64); }
  __shared__ float sA[4], sB[4];
  int wid = threadIdx.x >> 6, lane = threadIdx.x & 63;
  if (lane == 0) { sA[wid] = s1; sB[wid] = s2; }
  __syncthreads();
  float t1 = sA[0] + sA[1] + sA[2] + sA[3];
  float t2 = sB[0] + sB[1] + sB[2] + sB[3];
  float mean = t1 / (float)D;
  float var = t2 / (float)D - mean * mean;
  float rs = rsqrtf(var + EPSF);
  float* op = out ? out + (size_t)row * D : nullptr;
  unsigned short* obp = outb ? outb + (size_t)row * D : nullptr;
  for (int i = 0; i < per; ++i) {
    int d = threadIdx.x + (i << 8);
    float o = (vals[i] - mean) * rs * g[d] + bb[d];
    if (op)  op[d] = o;
    if (obp) obp[d] = f2bf(o);
  }
}

// ---------------- combine (<=2 expert slots) + optional add + LN (+relu) -> bf16/fp32
// fully vectorized: uint4/uint slot loads, float4/float2 residual, packed stores
template<int PER>
__global__ __launch_bounds__(256) void combine_ln(
    const unsigned short* __restrict__ slots,
    const int* __restrict__ ts0, const int* __restrict__ ts1,
    const float* __restrict__ sw,
    const float* __restrict__ addf,
    float* __restrict__ outf, unsigned short* __restrict__ outb,
    int relu_after,
    const float* __restrict__ g0, const float* __restrict__ g1,
    const float* __restrict__ g2, const float* __restrict__ g3,
    const float* __restrict__ bb0, const float* __restrict__ bb1,
    const float* __restrict__ bb2, const float* __restrict__ bb3)
{
  const int D = PER * 256;
  int row = blockIdx.x;
  int grp = (row & 1023) >> 8;
  const float* g  = grp == 0 ? g0  : grp == 1 ? g1  : grp == 2 ? g2  : g3;
  const float* bb = grp == 0 ? bb0 : grp == 1 ? bb1 : grp == 2 ? bb2 : bb3;
  int s0 = ts0[row], s1 = ts1[row];
  float w0 = s0 >= 0 ? sw[s0] : 0.f;
  float w1 = s1 >= 0 ? sw[s1] : 0.f;
  const unsigned short* p0 = slots + (size_t)(s0 >= 0 ? s0 : 0) * D;
  const unsigned short* p1 = slots + (size_t)(s1 >= 0 ? s1 : 0) * D;
  int base = threadIdx.x * PER;

  float addv[PER];
  if (addf) {
    const float* ap = addf + (size_t)row * D + base;
    if constexpr (PER == 8) {
      float4 t0 = *(const float4*)(ap);
      float4 t1 = *(const float4*)(ap + 4);
      addv[0]=t0.x; addv[1]=t0.y; addv[2]=t0.z; addv[3]=t0.w;
      addv[4]=t1.x; addv[5]=t1.y; addv[6]=t1.z; addv[7]=t1.w;
    } else {
      float2 t0 = *(const float2*)(ap);
      addv[0]=t0.x; addv[1]=t0.y;
    }
  } else {
    #pragma unroll
    for (int i = 0; i < PER; ++i) addv[i] = 0.f;
  }
  unsigned short b0[PER] = {}, b1[PER] = {};
  if (s0 >= 0) {
    if constexpr (PER == 8) *(uint4*)b0 = *(const uint4*)(p0 + base);
    else *(unsigned int*)b0 = *(const unsigned int*)(p0 + base);
  }
  if (s1 >= 0) {
    if constexpr (PER == 8) *(uint4*)b1 = *(const uint4*)(p1 + base);
    else *(unsigned int*)b1 = *(const unsigned int*)(p1 + base);
  }

  float vals[PER];
  float sm1 = 0.f, sm2 = 0.f;
  #pragma unroll
  for (int i = 0; i < PER; ++i) {
    float v = addv[i];
    if (s0 >= 0) v += w0 * bf2f(b0[i]);
    if (s1 >= 0) v += w1 * bf2f(b1[i]);
    vals[i] = v; sm1 += v; sm2 += v * v;
  }
  #pragma unroll
  for (int o = 32; o; o >>= 1) { sm1 += __shfl_xor(sm1, o, 64); sm2 += __shfl_xor(sm2, o, 64); }
  __shared__ float sA[4], sB[4];
  int wid = threadIdx.x >> 6, lane = threadIdx.x & 63;
  if (lane == 0) { sA[wid] = sm1; sB[wid] = sm2; }
  __syncthreads();
  float t1 = sA[0] + sA[1] + sA[2] + sA[3];
  float t2 = sB[0] + sB[1] + sB[2] + sB[3];
  float mean = t1 / (float)D;
  float var = t2 / (float)D - mean * mean;
  float rs = rsqrtf(var + EPSF);

  float ov[PER];
  #pragma unroll
  for (int i = 0; i < PER; ++i) {
    float o = (vals[i] - mean) * rs * g[base + i] + bb[base + i];
    if (relu_after) o = fmaxf(o, 0.f);
    ov[i] = o;
  }
  if (outf) {
    float* op = outf + (size_t)row * D + base;
    if constexpr (PER == 8) {
      *(float4*)(op)     = make_float4(ov[0], ov[1], ov[2], ov[3]);
      *(float4*)(op + 4) = make_float4(ov[4], ov[5], ov[6], ov[7]);
    } else {
      *(float2*)(op) = make_float2(ov[0], ov[1]);
    }
  }
  if (outb) {
    unsigned short* obp = outb + (size_t)row * D + base;
    if constexpr (PER == 8) {
      uint4 o;
      o.x = pk2(ov[0], ov[1]); o.y = pk2(ov[2], ov[3]);
      o.z = pk2(ov[4], ov[5]); o.w = pk2(ov[6], ov[7]);
      *(uint4*)obp = o;
    } else {
      *(unsigned int*)obp = pk2(ov[0], ov[1]);
    }
  }
}

// ---------------- gating stage 1
__global__ __launch_bounds__(256) void gate1(
    const float* __restrict__ xln, const float* __restrict__ wg,
    int* __restrict__ idx0, int* __restrict__ idx1,
    float* __restrict__ w0o, float* __restrict__ w1o)
{
  int wid = threadIdx.x >> 6, lane = threadIdx.x & 63;
  int tk = blockIdx.x * 4 + wid;
  int g = tk >> 11, t = tk & 2047;
  int b = t >> 8, j = t & 255;
  size_t row = (size_t)b * 1024 + g * 256 + j;
  const float* xp = xln + row * 512;
  float acc = -1e30f;
  if (lane < 24) {
    acc = 0.f;
    for (int d = 0; d < 512; ++d) acc += xp[d] * wg[d * 24 + lane];
  }
  float b0v = -1e30f, b1v = -1e30f; int i0 = 0, i1 = 0;
  for (int e = 0; e < 24; ++e) {
    float vv = __shfl(acc, e, 64);
    if (vv > b0v)      { b1v = b0v; i1 = i0; b0v = vv; i0 = e; }
    else if (vv > b1v) { b1v = vv; i1 = e; }
  }
  if (lane == 0) {
    float w0 = 1.0f / (1.0f + __expf(b1v - b0v));
    idx0[tk] = i0; idx1[tk] = i1; w0o[tk] = w0; w1o[tk] = 1.0f - w0;
  }
}

// ---------------- gating stage 2 (adds inverse token->slot maps ts0/ts1)
__global__ __launch_bounds__(64) void gate2(
    const int* __restrict__ idx0, const int* __restrict__ idx1,
    const float* __restrict__ w0, const float* __restrict__ w1,
    int* __restrict__ lrow, float* __restrict__ lw, int* __restrict__ counts,
    int* __restrict__ ts0, int* __restrict__ ts1)
{
  int pair = blockIdx.x; int g = pair / 24; int e = pair % 24;
  int lane = threadIdx.x;
  int base = g * TPG;
  unsigned long long lm = (lane == 63) ? 0x7fffffffffffffffULL : ((1ULL << lane) - 1ULL);
  int run = 0;
  for (int it = 0; it < TPG / 64; ++it) {
    int t = it * 64 + lane;
    bool m = (idx0[base + t] == e);
    unsigned long long mask = __ballot(m);
    int pre = __popcll(mask & lm);
    int rank = run + pre;
    if (m && rank < CAP) {
      int bq = t >> 8, j = t & 255;
      int rowidx = bq * 1024 + g * 256 + j;
      lrow[pair * CAPR + rank] = rowidx;
      lw[pair * CAPR + rank] = w0[base + t];
      ts0[rowidx] = pair * CAPR + rank;
    }
    run += __popcll(mask);
  }
  int total1 = run;
  int run2 = 0;
  for (int it = 0; it < TPG / 64; ++it) {
    int t = it * 64 + lane;
    bool m = (idx1[base + t] == e);
    unsigned long long mask = __ballot(m);
    int pre = __popcll(mask & lm);
    int rank2 = run2 + pre;
    if (m && (total1 + rank2) < CAP) {
      int bq = t >> 8, j = t & 255;
      int rowidx = bq * 1024 + g * 256 + j;
      lrow[pair * CAPR + total1 + rank2] = rowidx;
      lw[pair * CAPR + total1 + rank2] = w1[base + t];
      ts1[rowidx] = pair * CAPR + total1 + rank2;
    }
    run2 += __popcll(mask);
  }
  if (lane == 0) {
    int c1 = total1 < CAP ? total1 : CAP;
    int room = CAP - total1; if (room < 0) room = 0;
    int c2 = run2 < room ? run2 : room;
    counts[pair] = c1 + c2;
  }
}

extern "C" void kernel_launch(void* const* d_in, const int* in_sizes, int n_in,
                              void* d_out, int out_size, void* d_ws, size_t ws_size,
                              hipStream_t stream)
{
  const float* x   = (const float*)d_in[0];
  const float* wq  = (const float*)d_in[1];
  const float* wk  = (const float*)d_in[2];
  const float* wv  = (const float*)d_in[3];
  const float* wo  = (const float*)d_in[4];
  const float* ln_attn_g = (const float*)d_in[5];
  const float* ln_attn_b = (const float*)d_in[6];
  const float* wg1 = (const float*)d_in[7];
  const float* w1  = (const float*)d_in[8];
  const float* b1  = (const float*)d_in[9];
  const float* w2  = (const float*)d_in[11];
  const float* b2  = (const float*)d_in[12];
  const float* ln_out_g = (const float*)d_in[13];
  const float* ln_out_b = (const float*)d_in[14];
  const float* ln1g = (const float*)d_in[15]; const float* ln1b = (const float*)d_in[16];
  const float* ln2g = (const float*)d_in[17]; const float* ln2b = (const float*)d_in[18];
  const float* ln3g = (const float*)d_in[19]; const float* ln3b = (const float*)d_in[20];
  const float* ln4g = (const float*)d_in[21]; const float* ln4b = (const float*)d_in[22];

  char* ws = (char*)d_ws;
  const size_t MB = 1048576;
  unsigned short* wt1    = (unsigned short*)(ws + 0);
  unsigned short* hb2    = (unsigned short*)(ws + 0);            // after MoE1
  unsigned short* wt2    = (unsigned short*)(ws + 48 * MB);
  float*          ctxln  = (float*)(ws + 96 * MB);
  unsigned short* ctxlnb = (unsigned short*)(ws + 112 * MB);
  unsigned short* xbf    = (unsigned short*)(ws + 120 * MB);
  unsigned short* out1   = (unsigned short*)(ws + 120 * MB);     // after attn chain
  unsigned short* out2   = (unsigned short*)(ws + 120 * MB);     // after combine1
  unsigned short* qkvb   = (unsigned short*)(ws + 128 * MB);
  unsigned short* ctxb   = (unsigned short*)(ws + 152 * MB);
  unsigned short* wtqkv  = (unsigned short*)(ws + 160 * MB);
  unsigned short* wto    = (unsigned short*)(ws + 160 * MB + 1572864);
  float*          y0     = (float*)(ws + 162 * MB);
  char*  small = ws + 190 * MB;
  int*   idx0  = (int*)(small + 0);
  int*   idx1  = (int*)(small + 32768);
  float* w0a   = (float*)(small + 65536);
  float* w1a   = (float*)(small + 98304);
  int*   lrowp = (int*)(small + 131072);
  float* lwv   = (float*)(small + 198656);
  int*   cnts  = (int*)(small + 266240);
  int*   ts0   = (int*)(small + 270336);
  int*   ts1   = (int*)(small + 303104);

  dim3 blk(256);
  // ---- one-time conversions (bf16, B pre-transposed to [n][k]); qkv packed [1536][512]
  convw<<<dim3(8, 8, 1), blk, 0, stream>>>(wq, wtqkv, 512, 512);
  convw<<<dim3(8, 8, 1), blk, 0, stream>>>(wk, wtqkv + (size_t)512 * 512, 512, 512);
  convw<<<dim3(8, 8, 1), blk, 0, stream>>>(wv, wtqkv + (size_t)1024 * 512, 512, 512);
  convw<<<dim3(8, 8, 1), blk, 0, stream>>>(wo, wto, 512, 512);
  convw<<<dim3(32, 8, 24), blk, 0, stream>>>(w1, wt1, 512, 2048);
  convw<<<dim3(8, 32, 24), blk, 0, stream>>>(w2, wt2, 2048, 512);
  convx<<<4096, blk, 0, stream>>>(x, xbf);
  // ---- fused QKV projection (q scaled by 1/8 via per-col scale)
  mfma_gemm<<<dim3(12, 128, 1), blk, 0, stream>>>(xbf, DM, wtqkv, nullptr, nullptr, nullptr,
      nullptr, qkvb, nullptr, NTOK, 1536, DM, 0, 0.125f);
  // ---- attention
  attn_mfma<<<dim3(16, 64), blk, 0, stream>>>(qkvb, ctxb);
  // ---- y0 = relu(ctx@wo) + x
  mfma_gemm<<<dim3(4, 128, 1), blk, 0, stream>>>(ctxb, DM, wto, nullptr, nullptr, nullptr,
      y0, nullptr, x, NTOK, DM, DM, 1, 1.0f);
  // ---- ctx_ln = LN(y0), fp32 + bf16
  ln_kernel<<<8192, blk, 0, stream>>>(y0, ctxln, ctxlnb, DM, ln_attn_g, ln_attn_b);
  // ---- gating
  gate1<<<2048, blk, 0, stream>>>(ctxln, wg1, idx0, idx1, w0a, w1a);
  hipMemsetAsync(ts0, 0xFF, 65536, stream);      // ts0+ts1 = -1
  gate2<<<96, 64, 0, stream>>>(idx0, idx1, w0a, w1a, lrowp, lwv, cnts, ts0, ts1);
  // ---- MoE layer 1: per-slot out1[pair][CAPR][DI] = bf16(ctxln@W1[e] + b1[e])
  mfma_gemm<<<dim3(16, 3, 96), blk, 0, stream>>>(ctxlnb, DM, wt1, b1, lrowp, cnts,
      nullptr, out1, nullptr, 0, DI, DM, 3, 1.0f);
  // ---- hb2 = bf16(relu(LN_g(combine(out1))))
  combine_ln<8><<<8192, blk, 0, stream>>>(out1, ts0, ts1, lwv, nullptr,
      nullptr, hb2, 1, ln1g, ln2g, ln3g, ln4g, ln1b, ln2b, ln3b, ln4b);
  // ---- MoE layer 2: per-slot out2[pair][CAPR][DM] = bf16(hb2@W2[e] + b2[e])
  mfma_gemm<<<dim3(4, 3, 96), blk, 0, stream>>>(hb2, DI, wt2, b2, lrowp, cnts,
      nullptr, out2, nullptr, 0, DM, DI, 3, 1.0f);
  // ---- out = LN(combine(out2) + ctxln)
  combine_ln<2><<<8192, blk, 0, stream>>>(out2, ts0, ts1, lwv, ctxln,
      (float*)d_out, nullptr, 0, ln_out_g, ln_out_g, ln_out_g, ln_out_g,
      ln_out_b, ln_out_b, ln_out_b, ln_out_b);
}

// Round 5
// 686.851 us; speedup vs baseline: 1.2081x; 1.0181x over previous
//
#include <hip/hip_runtime.h>
#include <cstdint>

// ws layout (bytes, MB = 2^20):
// [0,48)    wt1 bf16 [24][2048][512]   : conv .. MoE1      } hb2 bf16 [0,32) : combine1 .. MoE2
// [48,96)   wt2 bf16 [24][512][2048]   : conv .. MoE2
// [96,112)  ctxln fp32                 : ctxLN .. final
// [112,120) ctxlnb bf16                : ctxLN .. MoE1
// [120,..)  early: xbf[120,128) qkvb[128,152) ctxb[152,160) wtqkv[160,161.5) wto[161.5,162) y0[162,178)
//           then: out1 bf16 [120,189.3) : MoE1 .. combine1 ; then out2 bf16 [120,137.3) : MoE2 .. final
// [190,..)  small gating buffers + ts0/ts1

#define NTOK 8192
#define DM   512
#define DI   2048
#define NEXP 24
#define TPG  2048
#define CAP  171
#define CAPR 176
#define EPSF 1e-6f

typedef __bf16 bf16x8 __attribute__((ext_vector_type(8)));
typedef float f32x4 __attribute__((ext_vector_type(4)));

static __device__ __forceinline__ unsigned short f2bf(float f) {
  unsigned int u = __builtin_bit_cast(unsigned int, f);
  u = (u + 0x7fffu + ((u >> 16) & 1u)) >> 16;
  return (unsigned short)u;
}
static __device__ __forceinline__ float bf2f(unsigned short u) {
  return __builtin_bit_cast(float, (unsigned int)u << 16);
}
static __device__ __forceinline__ unsigned int pk2(float a, float b) {
  return (unsigned int)f2bf(a) | ((unsigned int)f2bf(b) << 16);
}

// async global->LDS, 16B per lane; LDS dest is wave-uniform base + lane*16
static __device__ __forceinline__ void gload16(const unsigned short* g, unsigned short* l) {
  __builtin_amdgcn_global_load_lds(
      (const __attribute__((address_space(1))) void*)g,
      (__attribute__((address_space(3))) void*)l, 16, 0, 0);
}

// ---------------- weight transpose+convert: fp32 [e][K][N] -> bf16 [e][N][K]
__global__ __launch_bounds__(256) void convw(
    const float* __restrict__ in, unsigned short* __restrict__ out, int K, int N)
{
  __shared__ unsigned short T[64][65];
  int e = blockIdx.z;
  const float* ip = in + (size_t)e * K * N;
  unsigned short* op = out + (size_t)e * N * K;
  int n0 = blockIdx.x * 64, k0 = blockIdx.y * 64;
  int tid = threadIdx.x;
  #pragma unroll
  for (int i = 0; i < 16; ++i) {
    int lin = tid + i * 256;
    int k = lin >> 6, n = lin & 63;
    T[n][k] = f2bf(ip[(size_t)(k0 + k) * N + n0 + n]);
  }
  __syncthreads();
  #pragma unroll
  for (int i = 0; i < 16; ++i) {
    int lin = tid + i * 256;
    int n = lin >> 6, k = lin & 63;
    op[(size_t)(n0 + n) * K + k0 + k] = T[n][k];
  }
}

// ---------------- elementwise fp32 -> bf16
__global__ __launch_bounds__(256) void convx(
    const float* __restrict__ in, unsigned short* __restrict__ out)
{
  int i = blockIdx.x * 256 + threadIdx.x;
  float4 v = ((const float4*)in)[i];
  uint2 p;
  p.x = pk2(v.x, v.y); p.y = pk2(v.z, v.w);
  ((uint2*)out)[i] = p;
}

// ---------------- unified bf16-MFMA GEMM, 64m x 128n tile, BK=64, 4 waves
// single-buffered global_load_lds staging, XOR-swizzled LDS (24 KB -> 6 blocks/CU).
// 1D grid + XCD-aware decode: hardware assigns wg i -> XCD i%8 (round-robin);
// npair>1: all nx*ny blocks of a pair land on ONE XCD (expert working set <4MB L2);
// npair==1: all nx blocks sharing an A-panel (same m0) land on one XCD. ny%8==0 required.
// mode 0: Cb[m*N+col] = bf16(acc * (col<512 ? scale : 1))          (fused QKV)
// mode 1: Cf[m*N+col] = relu(acc) + Add[m*N+col]
// mode 3: Cb[pair*CAPR*N + m*N + col] = bf16(acc + bias[e*N+col])  (per-slot MoE out)
__global__ __launch_bounds__(256) void mfma_gemm(
    const unsigned short* __restrict__ A, int lda,
    const unsigned short* __restrict__ Bt,
    const float* __restrict__ bias,
    const int* __restrict__ lrow, const int* __restrict__ cnts,
    float* __restrict__ Cf, unsigned short* __restrict__ Cb,
    const float* __restrict__ Add,
    int M, int N, int K, int mode, float scale,
    int nx, int ny, int npair)
{
  __shared__ unsigned short As[64 * 64];
  __shared__ unsigned short Bs[128 * 64];
  int tid = threadIdx.x;
  int w = tid >> 6, lane = tid & 63, quad = lane >> 4, l16 = lane & 15;

  // ---- XCD-aware block decode
  int bid = blockIdx.x;
  int xcd = bid & 7, s = bid >> 3;
  int n0, m0, pair;
  if (npair > 1) {
    int nxy = nx * ny;
    int pidx = s / nxy;              // pair-group index on this XCD
    int inner = s - pidx * nxy;
    pair = xcd + (pidx << 3);
    n0 = (inner % nx) * 128;
    m0 = (inner / nx) * 64;
  } else {
    int midx = s / nx;
    int inner = s - midx * nx;
    m0 = (xcd + (midx << 3)) * 64;
    n0 = inner * 128;
    pair = 0;
  }
  int e = pair % NEXP;
  int count = cnts ? cnts[pair] : M;
  if (m0 >= count) return;
  const int* lr = lrow ? lrow + pair * CAPR : nullptr;

  int sub = lane >> 3;               // row-within-8-row wave chunk
  int gsw = (lane & 7) ^ sub;        // pre-swizzled source granule
  const unsigned short* aSrc[2];
  #pragma unroll
  for (int i = 0; i < 2; ++i) {
    int mm = m0 + i * 32 + w * 8 + sub;
    if (mm >= count) mm = count - 1;
    int rm = lr ? lr[mm] : mm;
    aSrc[i] = A + (size_t)rm * lda + gsw * 8;
  }
  const unsigned short* Bte = Bt + (size_t)e * N * K;
  const unsigned short* bSrc[4];
  #pragma unroll
  for (int i = 0; i < 4; ++i)
    bSrc[i] = Bte + (size_t)(n0 + i * 32 + w * 8 + sub) * K + gsw * 8;

  int wbase = w * 512;               // (w*8 rows) * 64 shorts

  f32x4 acc[4][2] = {};
  for (int t = 0; t < K; t += 64) {
    if (t) __syncthreads();          // previous tile fully consumed
    #pragma unroll
    for (int i = 0; i < 2; ++i) gload16(aSrc[i] + t, &As[i * 2048 + wbase]);
    #pragma unroll
    for (int i = 0; i < 4; ++i) gload16(bSrc[i] + t, &Bs[i * 2048 + wbase]);
    asm volatile("s_waitcnt vmcnt(0)" ::: "memory");
    __syncthreads();
    #pragma unroll
    for (int half = 0; half < 2; ++half) {
      int g8 = ((half * 4 + quad) ^ (l16 & 7)) * 8;   // swizzled read granule
      bf16x8 af[4];
      #pragma unroll
      for (int ms = 0; ms < 4; ++ms)
        af[ms] = *(const bf16x8*)&As[(ms * 16 + l16) * 64 + g8];
      bf16x8 bfr[2];
      #pragma unroll
      for (int ns = 0; ns < 2; ++ns)
        bfr[ns] = *(const bf16x8*)&Bs[(w * 32 + ns * 16 + l16) * 64 + g8];
      #pragma unroll
      for (int ms = 0; ms < 4; ++ms)
        #pragma unroll
        for (int ns = 0; ns < 2; ++ns)
          acc[ms][ns] = __builtin_amdgcn_mfma_f32_16x16x32_bf16(af[ms], bfr[ns], acc[ms][ns], 0, 0, 0);
    }
  }
  // ---- epilogue
  float bv[2] = {0.f, 0.f};
  unsigned short* Cbp = Cb;
  if (mode == 3) {
    #pragma unroll
    for (int ns = 0; ns < 2; ++ns)
      bv[ns] = bias[(size_t)e * N + n0 + w * 32 + ns * 16 + l16];
    Cbp = Cb + (size_t)pair * CAPR * N;
  }
  #pragma unroll
  for (int ms = 0; ms < 4; ++ms) {
    #pragma unroll
    for (int ns = 0; ns < 2; ++ns) {
      int col = n0 + w * 32 + ns * 16 + l16;
      #pragma unroll
      for (int r = 0; r < 4; ++r) {
        int m = m0 + ms * 16 + quad * 4 + r;
        if (mode == 0) {
          float sc = col < 512 ? scale : 1.0f;
          Cbp[(size_t)m * N + col] = f2bf(acc[ms][ns][r] * sc);
        } else if (mode == 1) {
          Cf[(size_t)m * N + col] = fmaxf(acc[ms][ns][r], 0.f) + Add[(size_t)m * N + col];
        } else {
          if (m < CAPR)
            Cbp[(size_t)m * N + col] = f2bf(acc[ms][ns][r] + bv[ns]);
        }
      }
    }
  }
}

// ---------------- MFMA bf16 flash attention; QKV packed [tok][1536], ctx bf16 [tok][512]
// 1D grid (1024 = 8 XCD * 128): all 16 q-tiles of one (b,h) land on one XCD (KV L2-resident)
__global__ __launch_bounds__(256) void attn_mfma(
    const unsigned short* __restrict__ QKV, unsigned short* __restrict__ ctx)
{
  __shared__ unsigned short Ks[64 * 72];
  __shared__ unsigned short Vt[64 * 72];
  __shared__ unsigned short Ps[4][16 * 72];
  int tid = threadIdx.x;
  int w = tid >> 6, lane = tid & 63, quad = lane >> 4, l16 = lane & 15;
  int bid = blockIdx.x;
  int xcd = bid & 7, s = bid >> 3;
  int bh = xcd + ((s >> 4) << 3);
  int qt = s & 15;
  int b = bh >> 3, h = bh & 7;
  size_t hoff = (size_t)h * 64;
  size_t tokbase = (size_t)b * 1024;

  int qrow = qt * 64 + w * 16 + l16;
  const unsigned short* qp = QKV + (tokbase + qrow) * 1536 + hoff + quad * 8;
  bf16x8 qa0 = *(const bf16x8*)(qp);
  bf16x8 qa1 = *(const bf16x8*)(qp + 32);

  f32x4 O[4] = {};
  float mrow[4], lrowv[4];
  #pragma unroll
  for (int r = 0; r < 4; ++r) { mrow[r] = -1e30f; lrowv[r] = 0.f; }

  for (int kv0 = 0; kv0 < 1024; kv0 += 64) {
    __syncthreads();
    {
      const unsigned short* kg = QKV + (tokbase + kv0) * 1536 + 512 + hoff;
      #pragma unroll
      for (int i = 0; i < 2; ++i) {
        int f = tid + i * 256;
        int key = f >> 3, c = f & 7;
        *(uint4*)&Ks[key * 72 + c * 8] = *(const uint4*)(kg + (size_t)key * 1536 + c * 8);
      }
      const unsigned short* vg = QKV + (tokbase + kv0) * 1536 + 1024 + hoff;
      int d = tid & 63;
      #pragma unroll
      for (int i = 0; i < 2; ++i) {
        int ko = (tid >> 6) + i * 4;
        const unsigned short* vq = vg + (size_t)ko * 8 * 1536 + d;
        unsigned int a0 = vq[0],         a1 = vq[1536];
        unsigned int a2 = vq[2 * 1536],  a3 = vq[3 * 1536];
        unsigned int a4 = vq[4 * 1536],  a5 = vq[5 * 1536];
        unsigned int a6 = vq[6 * 1536],  a7 = vq[7 * 1536];
        uint4 pk;
        pk.x = a0 | (a1 << 16); pk.y = a2 | (a3 << 16);
        pk.z = a4 | (a5 << 16); pk.w = a6 | (a7 << 16);
        *(uint4*)&Vt[d * 72 + ko * 8] = pk;
      }
    }
    __syncthreads();

    f32x4 s4[4];
    #pragma unroll
    for (int kt = 0; kt < 4; ++kt) {
      const unsigned short* kr = &Ks[(kt * 16 + l16) * 72 + quad * 8];
      bf16x8 kb0 = *(const bf16x8*)(kr);
      bf16x8 kb1 = *(const bf16x8*)(kr + 32);
      f32x4 z = {};
      z = __builtin_amdgcn_mfma_f32_16x16x32_bf16(qa0, kb0, z, 0, 0, 0);
      z = __builtin_amdgcn_mfma_f32_16x16x32_bf16(qa1, kb1, z, 0, 0, 0);
      s4[kt] = z;
    }

    #pragma unroll
    for (int r = 0; r < 4; ++r) {
      float mx = fmaxf(fmaxf(s4[0][r], s4[1][r]), fmaxf(s4[2][r], s4[3][r]));
      mx = fmaxf(mx, __shfl_xor(mx, 1, 64));
      mx = fmaxf(mx, __shfl_xor(mx, 2, 64));
      mx = fmaxf(mx, __shfl_xor(mx, 4, 64));
      mx = fmaxf(mx, __shfl_xor(mx, 8, 64));
      float mnew = fmaxf(mrow[r], mx);
      float alpha = __expf(mrow[r] - mnew);
      mrow[r] = mnew;
      float psum = 0.f;
      #pragma unroll
      for (int kt = 0; kt < 4; ++kt) {
        float p = __expf(s4[kt][r] - mnew);
        s4[kt][r] = p;
        psum += p;
      }
      psum += __shfl_xor(psum, 1, 64);
      psum += __shfl_xor(psum, 2, 64);
      psum += __shfl_xor(psum, 4, 64);
      psum += __shfl_xor(psum, 8, 64);
      lrowv[r] = lrowv[r] * alpha + psum;
      #pragma unroll
      for (int dt = 0; dt < 4; ++dt) O[dt][r] *= alpha;
    }

    #pragma unroll
    for (int kt = 0; kt < 4; ++kt)
      #pragma unroll
      for (int r = 0; r < 4; ++r)
        Ps[w][(quad * 4 + r) * 72 + kt * 16 + l16] = f2bf(s4[kt][r]);
    const unsigned short* pp = &Ps[w][l16 * 72 + quad * 8];
    bf16x8 pa0 = *(const bf16x8*)(pp);
    bf16x8 pa1 = *(const bf16x8*)(pp + 32);

    #pragma unroll
    for (int dt = 0; dt < 4; ++dt) {
      const unsigned short* vr = &Vt[(dt * 16 + l16) * 72 + quad * 8];
      bf16x8 vb0 = *(const bf16x8*)(vr);
      bf16x8 vb1 = *(const bf16x8*)(vr + 32);
      O[dt] = __builtin_amdgcn_mfma_f32_16x16x32_bf16(pa0, vb0, O[dt], 0, 0, 0);
      O[dt] = __builtin_amdgcn_mfma_f32_16x16x32_bf16(pa1, vb1, O[dt], 0, 0, 0);
    }
  }

  #pragma unroll
  for (int r = 0; r < 4; ++r) {
    float inv = 1.0f / lrowv[r];
    int row = qt * 64 + w * 16 + quad * 4 + r;
    unsigned short* cp = ctx + (tokbase + row) * 512 + hoff + l16;
    #pragma unroll
    for (int dt = 0; dt < 4; ++dt) cp[dt * 16] = f2bf(O[dt][r] * inv);
  }
}

// ---------------- layernorm (fp32 in, optional dual fp32/bf16 out)
__global__ __launch_bounds__(256) void ln_kernel(
    const float* __restrict__ in,
    float* __restrict__ out, unsigned short* __restrict__ outb,
    int D, const float* __restrict__ g, const float* __restrict__ bb)
{
  int row = blockIdx.x;
  const float* ip = in + (size_t)row * D;
  float vals[8];
  int per = D >> 8;
  float s1 = 0.f, s2 = 0.f;
  for (int i = 0; i < per; ++i) {
    int d = threadIdx.x + (i << 8);
    float vv = ip[d];
    vals[i] = vv; s1 += vv; s2 += vv * vv;
  }
  #pragma unroll
  for (int o = 32; o; o >>= 1) { s1 += __shfl_xor(s1, o, 64); s2 += __shfl_xor(s2, o, 64); }
  __shared__ float sA[4], sB[4];
  int wid = threadIdx.x >> 6, lane = threadIdx.x & 63;
  if (lane == 0) { sA[wid] = s1; sB[wid] = s2; }
  __syncthreads();
  float t1 = sA[0] + sA[1] + sA[2] + sA[3];
  float t2 = sB[0] + sB[1] + sB[2] + sB[3];
  float mean = t1 / (float)D;
  float var = t2 / (float)D - mean * mean;
  float rs = rsqrtf(var + EPSF);
  float* op = out ? out + (size_t)row * D : nullptr;
  unsigned short* obp = outb ? outb + (size_t)row * D : nullptr;
  for (int i = 0; i < per; ++i) {
    int d = threadIdx.x + (i << 8);
    float o = (vals[i] - mean) * rs * g[d] + bb[d];
    if (op)  op[d] = o;
    if (obp) obp[d] = f2bf(o);
  }
}

// ---------------- combine (<=2 expert slots) + optional add + LN (+relu) -> bf16/fp32
template<int PER>
__global__ __launch_bounds__(256) void combine_ln(
    const unsigned short* __restrict__ slots,
    const int* __restrict__ ts0, const int* __restrict__ ts1,
    const float* __restrict__ sw,
    const float* __restrict__ addf,
    float* __restrict__ outf, unsigned short* __restrict__ outb,
    int relu_after,
    const float* __restrict__ g0, const float* __restrict__ g1,
    const float* __restrict__ g2, const float* __restrict__ g3,
    const float* __restrict__ bb0, const float* __restrict__ bb1,
    const float* __restrict__ bb2, const float* __restrict__ bb3)
{
  const int D = PER * 256;
  int row = blockIdx.x;
  int grp = (row & 1023) >> 8;
  const float* g  = grp == 0 ? g0  : grp == 1 ? g1  : grp == 2 ? g2  : g3;
  const float* bb = grp == 0 ? bb0 : grp == 1 ? bb1 : grp == 2 ? bb2 : bb3;
  int s0 = ts0[row], s1 = ts1[row];
  float w0 = s0 >= 0 ? sw[s0] : 0.f;
  float w1 = s1 >= 0 ? sw[s1] : 0.f;
  const unsigned short* p0 = slots + (size_t)(s0 >= 0 ? s0 : 0) * D;
  const unsigned short* p1 = slots + (size_t)(s1 >= 0 ? s1 : 0) * D;
  int base = threadIdx.x * PER;

  float addv[PER];
  if (addf) {
    const float* ap = addf + (size_t)row * D + base;
    if constexpr (PER == 8) {
      float4 t0 = *(const float4*)(ap);
      float4 t1 = *(const float4*)(ap + 4);
      addv[0]=t0.x; addv[1]=t0.y; addv[2]=t0.z; addv[3]=t0.w;
      addv[4]=t1.x; addv[5]=t1.y; addv[6]=t1.z; addv[7]=t1.w;
    } else {
      float2 t0 = *(const float2*)(ap);
      addv[0]=t0.x; addv[1]=t0.y;
    }
  } else {
    #pragma unroll
    for (int i = 0; i < PER; ++i) addv[i] = 0.f;
  }
  unsigned short b0[PER] = {}, b1[PER] = {};
  if (s0 >= 0) {
    if constexpr (PER == 8) *(uint4*)b0 = *(const uint4*)(p0 + base);
    else *(unsigned int*)b0 = *(const unsigned int*)(p0 + base);
  }
  if (s1 >= 0) {
    if constexpr (PER == 8) *(uint4*)b1 = *(const uint4*)(p1 + base);
    else *(unsigned int*)b1 = *(const unsigned int*)(p1 + base);
  }

  float vals[PER];
  float sm1 = 0.f, sm2 = 0.f;
  #pragma unroll
  for (int i = 0; i < PER; ++i) {
    float v = addv[i];
    if (s0 >= 0) v += w0 * bf2f(b0[i]);
    if (s1 >= 0) v += w1 * bf2f(b1[i]);
    vals[i] = v; sm1 += v; sm2 += v * v;
  }
  #pragma unroll
  for (int o = 32; o; o >>= 1) { sm1 += __shfl_xor(sm1, o, 64); sm2 += __shfl_xor(sm2, o, 64); }
  __shared__ float sA[4], sB[4];
  int wid = threadIdx.x >> 6, lane = threadIdx.x & 63;
  if (lane == 0) { sA[wid] = sm1; sB[wid] = sm2; }
  __syncthreads();
  float t1 = sA[0] + sA[1] + sA[2] + sA[3];
  float t2 = sB[0] + sB[1] + sB[2] + sB[3];
  float mean = t1 / (float)D;
  float var = t2 / (float)D - mean * mean;
  float rs = rsqrtf(var + EPSF);

  float ov[PER];
  #pragma unroll
  for (int i = 0; i < PER; ++i) {
    float o = (vals[i] - mean) * rs * g[base + i] + bb[base + i];
    if (relu_after) o = fmaxf(o, 0.f);
    ov[i] = o;
  }
  if (outf) {
    float* op = outf + (size_t)row * D + base;
    if constexpr (PER == 8) {
      *(float4*)(op)     = make_float4(ov[0], ov[1], ov[2], ov[3]);
      *(float4*)(op + 4) = make_float4(ov[4], ov[5], ov[6], ov[7]);
    } else {
      *(float2*)(op) = make_float2(ov[0], ov[1]);
    }
  }
  if (outb) {
    unsigned short* obp = outb + (size_t)row * D + base;
    if constexpr (PER == 8) {
      uint4 o;
      o.x = pk2(ov[0], ov[1]); o.y = pk2(ov[2], ov[3]);
      o.z = pk2(ov[4], ov[5]); o.w = pk2(ov[6], ov[7]);
      *(uint4*)obp = o;
    } else {
      *(unsigned int*)obp = pk2(ov[0], ov[1]);
    }
  }
}

// ---------------- gating stage 1
__global__ __launch_bounds__(256) void gate1(
    const float* __restrict__ xln, const float* __restrict__ wg,
    int* __restrict__ idx0, int* __restrict__ idx1,
    float* __restrict__ w0o, float* __restrict__ w1o)
{
  int wid = threadIdx.x >> 6, lane = threadIdx.x & 63;
  int tk = blockIdx.x * 4 + wid;
  int g = tk >> 11, t = tk & 2047;
  int b = t >> 8, j = t & 255;
  size_t row = (size_t)b * 1024 + g * 256 + j;
  const float* xp = xln + row * 512;
  float acc = -1e30f;
  if (lane < 24) {
    acc = 0.f;
    for (int d = 0; d < 512; ++d) acc += xp[d] * wg[d * 24 + lane];
  }
  float b0v = -1e30f, b1v = -1e30f; int i0 = 0, i1 = 0;
  for (int e = 0; e < 24; ++e) {
    float vv = __shfl(acc, e, 64);
    if (vv > b0v)      { b1v = b0v; i1 = i0; b0v = vv; i0 = e; }
    else if (vv > b1v) { b1v = vv; i1 = e; }
  }
  if (lane == 0) {
    float w0 = 1.0f / (1.0f + __expf(b1v - b0v));
    idx0[tk] = i0; idx1[tk] = i1; w0o[tk] = w0; w1o[tk] = 1.0f - w0;
  }
}

// ---------------- gating stage 2 (adds inverse token->slot maps ts0/ts1)
__global__ __launch_bounds__(64) void gate2(
    const int* __restrict__ idx0, const int* __restrict__ idx1,
    const float* __restrict__ w0, const float* __restrict__ w1,
    int* __restrict__ lrow, float* __restrict__ lw, int* __restrict__ counts,
    int* __restrict__ ts0, int* __restrict__ ts1)
{
  int pair = blockIdx.x; int g = pair / 24; int e = pair % 24;
  int lane = threadIdx.x;
  int base = g * TPG;
  unsigned long long lm = (lane == 63) ? 0x7fffffffffffffffULL : ((1ULL << lane) - 1ULL);
  int run = 0;
  for (int it = 0; it < TPG / 64; ++it) {
    int t = it * 64 + lane;
    bool m = (idx0[base + t] == e);
    unsigned long long mask = __ballot(m);
    int pre = __popcll(mask & lm);
    int rank = run + pre;
    if (m && rank < CAP) {
      int bq = t >> 8, j = t & 255;
      int rowidx = bq * 1024 + g * 256 + j;
      lrow[pair * CAPR + rank] = rowidx;
      lw[pair * CAPR + rank] = w0[base + t];
      ts0[rowidx] = pair * CAPR + rank;
    }
    run += __popcll(mask);
  }
  int total1 = run;
  int run2 = 0;
  for (int it = 0; it < TPG / 64; ++it) {
    int t = it * 64 + lane;
    bool m = (idx1[base + t] == e);
    unsigned long long mask = __ballot(m);
    int pre = __popcll(mask & lm);
    int rank2 = run2 + pre;
    if (m && (total1 + rank2) < CAP) {
      int bq = t >> 8, j = t & 255;
      int rowidx = bq * 1024 + g * 256 + j;
      lrow[pair * CAPR + total1 + rank2] = rowidx;
      lw[pair * CAPR + total1 + rank2] = w1[base + t];
      ts1[rowidx] = pair * CAPR + total1 + rank2;
    }
    run2 += __popcll(mask);
  }
  if (lane == 0) {
    int c1 = total1 < CAP ? total1 : CAP;
    int room = CAP - total1; if (room < 0) room = 0;
    int c2 = run2 < room ? run2 : room;
    counts[pair] = c1 + c2;
  }
}

extern "C" void kernel_launch(void* const* d_in, const int* in_sizes, int n_in,
                              void* d_out, int out_size, void* d_ws, size_t ws_size,
                              hipStream_t stream)
{
  const float* x   = (const float*)d_in[0];
  const float* wq  = (const float*)d_in[1];
  const float* wk  = (const float*)d_in[2];
  const float* wv  = (const float*)d_in[3];
  const float* wo  = (const float*)d_in[4];
  const float* ln_attn_g = (const float*)d_in[5];
  const float* ln_attn_b = (const float*)d_in[6];
  const float* wg1 = (const float*)d_in[7];
  const float* w1  = (const float*)d_in[8];
  const float* b1  = (const float*)d_in[9];
  const float* w2  = (const float*)d_in[11];
  const float* b2  = (const float*)d_in[12];
  const float* ln_out_g = (const float*)d_in[13];
  const float* ln_out_b = (const float*)d_in[14];
  const float* ln1g = (const float*)d_in[15]; const float* ln1b = (const float*)d_in[16];
  const float* ln2g = (const float*)d_in[17]; const float* ln2b = (const float*)d_in[18];
  const float* ln3g = (const float*)d_in[19]; const float* ln3b = (const float*)d_in[20];
  const float* ln4g = (const float*)d_in[21]; const float* ln4b = (const float*)d_in[22];

  char* ws = (char*)d_ws;
  const size_t MB = 1048576;
  unsigned short* wt1    = (unsigned short*)(ws + 0);
  unsigned short* hb2    = (unsigned short*)(ws + 0);            // after MoE1
  unsigned short* wt2    = (unsigned short*)(ws + 48 * MB);
  float*          ctxln  = (float*)(ws + 96 * MB);
  unsigned short* ctxlnb = (unsigned short*)(ws + 112 * MB);
  unsigned short* xbf    = (unsigned short*)(ws + 120 * MB);
  unsigned short* out1   = (unsigned short*)(ws + 120 * MB);     // after attn chain
  unsigned short* out2   = (unsigned short*)(ws + 120 * MB);     // after combine1
  unsigned short* qkvb   = (unsigned short*)(ws + 128 * MB);
  unsigned short* ctxb   = (unsigned short*)(ws + 152 * MB);
  unsigned short* wtqkv  = (unsigned short*)(ws + 160 * MB);
  unsigned short* wto    = (unsigned short*)(ws + 160 * MB + 1572864);
  float*          y0     = (float*)(ws + 162 * MB);
  char*  small = ws + 190 * MB;
  int*   idx0  = (int*)(small + 0);
  int*   idx1  = (int*)(small + 32768);
  float* w0a   = (float*)(small + 65536);
  float* w1a   = (float*)(small + 98304);
  int*   lrowp = (int*)(small + 131072);
  float* lwv   = (float*)(small + 198656);
  int*   cnts  = (int*)(small + 266240);
  int*   ts0   = (int*)(small + 270336);
  int*   ts1   = (int*)(small + 303104);

  dim3 blk(256);
  // ---- one-time conversions (bf16, B pre-transposed to [n][k]); qkv packed [1536][512]
  convw<<<dim3(8, 8, 1), blk, 0, stream>>>(wq, wtqkv, 512, 512);
  convw<<<dim3(8, 8, 1), blk, 0, stream>>>(wk, wtqkv + (size_t)512 * 512, 512, 512);
  convw<<<dim3(8, 8, 1), blk, 0, stream>>>(wv, wtqkv + (size_t)1024 * 512, 512, 512);
  convw<<<dim3(8, 8, 1), blk, 0, stream>>>(wo, wto, 512, 512);
  convw<<<dim3(32, 8, 24), blk, 0, stream>>>(w1, wt1, 512, 2048);
  convw<<<dim3(8, 32, 24), blk, 0, stream>>>(w2, wt2, 2048, 512);
  convx<<<4096, blk, 0, stream>>>(x, xbf);
  // ---- fused QKV projection (q scaled by 1/8 via per-col scale); grid 12*128
  mfma_gemm<<<1536, blk, 0, stream>>>(xbf, DM, wtqkv, nullptr, nullptr, nullptr,
      nullptr, qkvb, nullptr, NTOK, 1536, DM, 0, 0.125f, 12, 128, 1);
  // ---- attention (grid 16*64 -> 1D XCD-grouped)
  attn_mfma<<<1024, blk, 0, stream>>>(qkvb, ctxb);
  // ---- y0 = relu(ctx@wo) + x ; grid 4*128
  mfma_gemm<<<512, blk, 0, stream>>>(ctxb, DM, wto, nullptr, nullptr, nullptr,
      y0, nullptr, x, NTOK, DM, DM, 1, 1.0f, 4, 128, 1);
  // ---- ctx_ln = LN(y0), fp32 + bf16
  ln_kernel<<<8192, blk, 0, stream>>>(y0, ctxln, ctxlnb, DM, ln_attn_g, ln_attn_b);
  // ---- gating
  gate1<<<2048, blk, 0, stream>>>(ctxln, wg1, idx0, idx1, w0a, w1a);
  hipMemsetAsync(ts0, 0xFF, 65536, stream);      // ts0+ts1 = -1
  gate2<<<96, 64, 0, stream>>>(idx0, idx1, w0a, w1a, lrowp, lwv, cnts, ts0, ts1);
  // ---- MoE layer 1: per-slot out1[pair][CAPR][DI] = bf16(ctxln@W1[e] + b1[e]); grid 16*3*96
  mfma_gemm<<<4608, blk, 0, stream>>>(ctxlnb, DM, wt1, b1, lrowp, cnts,
      nullptr, out1, nullptr, 0, DI, DM, 3, 1.0f, 16, 3, 96);
  // ---- hb2 = bf16(relu(LN_g(combine(out1))))
  combine_ln<8><<<8192, blk, 0, stream>>>(out1, ts0, ts1, lwv, nullptr,
      nullptr, hb2, 1, ln1g, ln2g, ln3g, ln4g, ln1b, ln2b, ln3b, ln4b);
  // ---- MoE layer 2: per-slot out2[pair][CAPR][DM] = bf16(hb2@W2[e] + b2[e]); grid 4*3*96
  mfma_gemm<<<1152, blk, 0, stream>>>(hb2, DI, wt2, b2, lrowp, cnts,
      nullptr, out2, nullptr, 0, DM, DI, 3, 1.0f, 4, 3, 96);
  // ---- out = LN(combine(out2) + ctxln)
  combine_ln<2><<<8192, blk, 0, stream>>>(out2, ts0, ts1, lwv, ctxln,
      (float*)d_out, nullptr, 0, ln_out_g, ln_out_g, ln_out_g, ln_out_g,
      ln_out_b, ln_out_b, ln_out_b, ln_out_b);
}